// Round 10
// baseline (449.403 us; speedup 1.0000x reference)
//
#include <hip/hip_runtime.h>
#include <stdint.h>

#define EPSF 1e-5f

typedef __bf16 bf16;
typedef __attribute__((ext_vector_type(8))) __bf16 bf16x8;
typedef __attribute__((ext_vector_type(4))) float f32x4;
typedef __attribute__((ext_vector_type(16))) float f32x16;

// async global->LDS, 16B per lane, dest = wave-uniform base + lane*16 (linear)
#define GL16(src, dst) __builtin_amdgcn_global_load_lds( \
    (const __attribute__((address_space(1))) void*)(src), \
    (__attribute__((address_space(3))) void*)(dst), 16, 0, 0)
// IR+ISA ordering fence for memory ops (pins GL16 issue order vs A-loads/ds_reads)
#define MEMFENCE() asm volatile("" ::: "memory")

template<int N> __device__ __forceinline__ void vwait() {
  static_assert(N == 2 || N == 3 || N == 4 || N == 6, "unsupported vmcnt");
  if constexpr (N == 2) asm volatile("s_waitcnt vmcnt(2)" ::: "memory");
  else if constexpr (N == 3) asm volatile("s_waitcnt vmcnt(3)" ::: "memory");
  else if constexpr (N == 4) asm volatile("s_waitcnt vmcnt(4)" ::: "memory");
  else asm volatile("s_waitcnt vmcnt(6)" ::: "memory");
}

// ---------------- fused prep: quant (blocks 0..383) + transpose (384..8575) -----
// g==0 (conv1) prepack targets the 32x32x16 A-fragment layout:
//   lane = ((c>>3)&1)*32 + (o&31), k-sub ks2 = pos*16 + (c>>4), mt = o>>5 (6 tiles)
// g==1/2 keep the 16x16x32 layout (lane = kq*16 + (o&15)).
struct QArgs {
  const float* w[5];
  const float* g[5];
  const float* bb[5];
  const float* m[5];
  const float* v[5];
  bf16* wpk[3];
  float* alpha[3];
  float* beta[3];
};

__global__ __launch_bounds__(256)
void prep_k(QArgs qa, const float* __restrict__ x, bf16* __restrict__ xT,
            float* __restrict__ zp) {
  __shared__ int red[2][4];
  __shared__ float tile[64 * 66];
  const int tid = threadIdx.x;
  if (blockIdx.x == 0 && tid < 32) zp[tid] = 0.0f;   // 128B zero page

  if (blockIdx.x < 384) {
    // ---------------- quant branch ----------------
    const int blk = blockIdx.x;
    int layer, o;
    if (blk < 128)      { layer = 0; o = blk; }
    else if (blk < 192) { layer = 1; o = blk - 128; }
    else if (blk < 256) { layer = 2; o = blk - 192; }
    else if (blk < 320) { layer = 3; o = blk - 256; }
    else                { layer = 4; o = blk - 320; }
    const int I_[5]     = {256, 256, 64, 64, 64};
    const int gemm_[5]  = {0, 0, 1, 1, 2};
    const int obase_[5] = {0, 128, 0, 64, 0};
    const int gNMT[3]   = {6, 8, 4};           // g0: 32-ch tiles; g1/g2: 16-ch
    const int I = I_[layer];
    const int n = I * 9;                       // 2304 or 576
    const float* w = qa.w[layer] + (size_t)o * n;

    unsigned key[9];
#pragma unroll
    for (int j = 0; j < 9; ++j) key[j] = 0xFFFFFFFFu;   // pad: never < cand
    {
      int c2 = 0;
      for (int i = tid; i < n; i += 256) key[c2++] = __float_as_uint(fabsf(w[i]));
    }

    const int wv = tid >> 6;
    unsigned pfx[2] = {0u, 0u};
    const int rank0 = n / 2 - 1, rank1 = n / 2;
    int pp = 0;
    for (int bit = 31; bit >= 0; --bit) {
      const unsigned c0 = pfx[0] | (1u << bit);
      const unsigned c1 = pfx[1] | (1u << bit);
      int loc = 0;
#pragma unroll
      for (int j = 0; j < 9; ++j)
        loc += (key[j] < c0 ? 1 : 0) + (key[j] < c1 ? 0x10000 : 0);
      loc += __shfl_xor(loc, 32); loc += __shfl_xor(loc, 16);
      loc += __shfl_xor(loc, 8);  loc += __shfl_xor(loc, 4);
      loc += __shfl_xor(loc, 2);  loc += __shfl_xor(loc, 1);
      if ((tid & 63) == 0) red[pp][wv] = loc;
      __syncthreads();
      const int tot = red[pp][0] + red[pp][1] + red[pp][2] + red[pp][3];
      if ((tot & 0xFFFF) <= rank0) pfx[0] = c0;
      if ((tot >> 16)    <= rank1) pfx[1] = c1;
      pp ^= 1;
    }
    const float s =
        fmaxf(0.5f * (__uint_as_float(pfx[0]) + __uint_as_float(pfx[1])), EPSF);

    const int g  = gemm_[layer];
    const int ob = obase_[layer];
    const int NMT = gNMT[g];
    if (tid == 0) {
      float inv = qa.g[layer][o] / sqrtf(qa.v[layer][o] + EPSF);
      qa.alpha[g][ob + o] = s * inv;
      qa.beta[g][ob + o]  = qa.bb[layer][o] - qa.m[layer][o] * inv;
    }
    const int og  = ob + o;
    bf16* wp = qa.wpk[g];
    for (int i = tid; i < n; i += 256) {
      float t = rintf(w[i] / s);
      t = fmaxf(-1.f, fminf(1.f, t));
      int c = i / 9, pos = i % 9;
      if (g == 0) {                            // 32x32x16 fragment layout
        int ks2 = pos * 16 + (c >> 4);
        int l   = ((c >> 3) & 1) * 32 + (og & 31);
        int mt  = og >> 5;
        wp[((size_t)((ks2 * 6 + mt) * 64 + l)) * 8 + (c & 7)] = (bf16)t;
      } else {                                 // 16x16x32 fragment layout
        int k = pos * I + c;
        int ks = k >> 5, kq = (k >> 3) & 3, jj = k & 7;
        int mt = og >> 4, l16 = og & 15;
        wp[((size_t)((ks * NMT + mt) * 64 + kq * 16 + l16)) * 8 + jj] = (bf16)t;
      }
    }
    return;
  }

  // ---------------- transpose branch ----------------
  const int blk = blockIdx.x - 384;
  const int cg = blk & 3;
  const int h  = (blk >> 2) & 63;
  const int b  = blk >> 8;
  const int w4 = (tid & 15) * 4;
  const int cb = tid >> 4;               // 0..15
#pragma unroll
  for (int p = 0; p < 4; ++p) {
    int c = cb + p * 16;
    const float4 v =
        *(const float4*)&x[(((size_t)(b * 256 + cg * 64 + c)) * 64 + h) * 64 + w4];
    tile[(w4 + 0) * 66 + c] = v.x;
    tile[(w4 + 1) * 66 + c] = v.y;
    tile[(w4 + 2) * 66 + c] = v.z;
    tile[(w4 + 3) * 66 + c] = v.w;
  }
  __syncthreads();
#pragma unroll
  for (int p = 0; p < 2; ++p) {
    int id = tid + p * 256;
    int c8 = id & 7, w2 = id >> 3;
    const float* src = &tile[w2 * 66 + c8 * 8];
    float2 f0 = *(const float2*)(src + 0);
    float2 f1 = *(const float2*)(src + 2);
    float2 f2 = *(const float2*)(src + 4);
    float2 f3 = *(const float2*)(src + 6);
    bf16x8 v;
    v[0] = (bf16)f0.x; v[1] = (bf16)f0.y; v[2] = (bf16)f1.x; v[3] = (bf16)f1.y;
    v[4] = (bf16)f2.x; v[5] = (bf16)f2.y; v[6] = (bf16)f3.x; v[7] = (bf16)f3.y;
    *(bf16x8*)&xT[(((size_t)(b * 64 + h)) * 64 + w2) * 256 + cg * 64 + c8 * 8] = v;
  }
}

// ---------------- conv1: 32x32x16 MFMA implicit-GEMM + BN + SiLU ----------------
// 512 thr = 8 waves; block = 2 rows x 64 px x 192 ch. Wave (rw,nn,mg) owns 3
// 32x32 tiles: 96 ch x 32 px x 1 row. Per c-iter per wave: 18 B ds_read_b128
// (HALF the 16x16 shape's 36) + 54 MFMA @ 32x32x16 (higher rate) -> serial-sum
// window shrinks 16K->~11K cyc. B-frag: lane l: px=l&31, ch=(l>>5)*8.., one read
// per (tap,k-half), reused across 3 m-tiles. kh2 selects 32B chunk via addr XOR
// (bases 64-aligned). A: 3-slot ring at (tap,half) granularity, prefetch 2 ahead
// (~290cyc L2 cover); cross-iter u16/u17 loads fly over the barrier.
// vmcnt ledger: at every barrier the newest 6 VMEM = those cross A-loads (ci=0:
// the fr0/fr1 preload); all GL16s are >=54 loads older -> vwait<6> uniform.
// C/D (m101): col=lane&31, row=(reg&3)+8*(reg>>2)+4*(lane>>5).
__global__ __launch_bounds__(512, 4)
void conv1_k(const bf16* __restrict__ xin,   // [B][64][64][256] c-minor bf16
             const bf16* __restrict__ wpk,
             const float* __restrict__ alpha,
             const float* __restrict__ beta,
             float* __restrict__ out,
             bf16* __restrict__ padout,      // [B][64][64][64] c-minor bf16
             const bf16* __restrict__ zpage) {
  __shared__ __align__(16) union U {
    bf16 xs[2][8704];   // 2 x 1088 chunks x 16B = 34.8 KB
    bf16 ep[128 * 72];  // 18.4 KB epilogue transpose buffer
  } sm;

  const int tid  = threadIdx.x;
  const int wave = tid >> 6;
  const int lane = tid & 63;
  const int l31  = lane & 31;
  const int b5   = lane >> 5;
  const int rw   = wave >> 2;            // row (0/1)
  const int nn   = (wave >> 1) & 1;      // n-tile (32 px)
  const int mg   = wave & 1;             // m-group: tiles {0,1,2} or {3,4,5}
  const int mt0  = mg * 3;
  const int b    = blockIdx.x >> 5;
  const int h0   = (blockIdx.x & 31) << 1;

  // staging map (identical to proven R8): 1056 live chunks = 4r x 66c x 4ch
  const bf16* srcp[3];
  int step[3];
#pragma unroll
  for (int p = 0; p < 3; ++p) {
    const int id = tid + p * 512;
    const int c8p = id & 3, rj = id >> 2;
    const int j = rj % 66, r = rj / 66;
    const int hh = h0 + r - 1, ww = j - 1;
    const bool v = (id < 1056) && ((unsigned)hh < 64u) && ((unsigned)ww < 64u);
    const int c8 = c8p ^ ((j >> 1) & 3);          // inverse swizzle on source
    srcp[p] = v ? &xin[(((size_t)(b * 64 + hh)) * 64 + ww) * 256 + c8 * 8] : zpage;
    step[p] = v ? 32 : 0;
  }
  auto stage = [&](char* base) {
    GL16(srcp[0], base + (tid) * 16);
    GL16(srcp[1], base + (512 + tid) * 16);
    if (wave == 0) GL16(srcp[2], base + (1024 + tid) * 16);
  };

  // B base addrs per kw (buf0, kh=0, kh2=0): chunk = b5, swz = (col>>1)&3
  int Caddr[3];
#pragma unroll
  for (int kw = 0; kw < 3; ++kw) {
    const int col = nn * 32 + l31 + kw;
    Caddr[kw] = (rw * 66 + col) * 64 + ((b5 ^ ((col >> 1) & 3)) << 4);
  }

  char* const lds0 = (char*)&sm.xs[0][0];

  // prologue: stage buf0; preload A ring slots 0,1 (ci=0, u=0/1)
  stage(lds0);
  MEMFENCE();
#pragma unroll
  for (int p = 0; p < 3; ++p) srcp[p] += step[p];

  const char* wb = (const char*)wpk + lane * 16;   // + ci*12288 later
  bf16x8 fr[3][3];
#pragma unroll
  for (int mm = 0; mm < 3; ++mm) {
    fr[0][mm] = *(const bf16x8*)(wb + (mt0 + mm) * 1024);              // ks2=0
    fr[1][mm] = *(const bf16x8*)(wb + 6144 + (mt0 + mm) * 1024);       // ks2=1
  }

  f32x16 acc[3] = {};
  int tog = 17408;
  int cbase = 0;                          // ci * 12288 (A byte offset)

  for (int ci = 0; ci < 8; ++ci) {
    vwait<6>();                           // GL16s retired; 6 ring A-loads in flight
    __builtin_amdgcn_s_barrier();
    if (ci + 1 < 8) {
      stage(lds0 + (((ci + 1) & 1) ? 17408 : 0));
#pragma unroll
      for (int p = 0; p < 3; ++p) srcp[p] += step[p];
    }
    MEMFENCE();                           // GL16 issue pinned before A/B reads
    bf16x8 bb0, bb1;
    bb0 = *(const bf16x8*)(lds0 + Caddr[0]);          // u=0: pos0,kh2=0
    __builtin_amdgcn_s_setprio(1);
#pragma unroll
    for (int u = 0; u < 18; ++u) {
      if (u < 17) {                       // B prefetch u+1
        const int un = u + 1, posn = un >> 1, kh2n = un & 1;
        const int khn = posn / 3, kwn = posn % 3;
        const bf16x8 v =
            *(const bf16x8*)(lds0 + ((Caddr[kwn] + khn * 4224) ^ (kh2n << 5)));
        if (un & 1) bb1 = v; else bb0 = v;
      }
      const int ut = u + 2;               // A ring prefetch 2 ahead
      if (ut <= 17) {
        const int posn = ut >> 1, kh2n = ut & 1;
#pragma unroll
        for (int mm = 0; mm < 3; ++mm)
          fr[ut % 3][mm] = *(const bf16x8*)(wb + cbase + posn * 98304 +
                                            kh2n * 6144 + (mt0 + mm) * 1024);
      } else if (ci + 1 < 8) {            // cross-iter u0/u1, fly over barrier
        const int uu = ut - 18, posn = uu >> 1, kh2n = uu & 1;
#pragma unroll
        for (int mm = 0; mm < 3; ++mm)
          fr[ut % 3][mm] = *(const bf16x8*)(wb + cbase + 12288 + posn * 98304 +
                                            kh2n * 6144 + (mt0 + mm) * 1024);
      }
      const bf16x8 bc = (u & 1) ? bb1 : bb0;
#pragma unroll
      for (int mm = 0; mm < 3; ++mm)
        acc[mm] = __builtin_amdgcn_mfma_f32_32x32x16_bf16(fr[u % 3][mm], bc,
                                                          acc[mm], 0, 0, 0);
    }
    __builtin_amdgcn_s_setprio(0);
#pragma unroll
    for (int kw = 0; kw < 3; ++kw) Caddr[kw] += tog;   // buffer toggle
    tog = -tog;
    cbase += 12288;
  }

  // epilogue: BN + SiLU; fp32 NCHW for o<128, bf16 c-minor stem for o>=128
  const int h  = h0 + rw;
  const int wv = nn * 32 + l31;
#pragma unroll
  for (int mm = 0; mm < 3; ++mm) {
    const int mt = mt0 + mm, ob = mt * 32;
#pragma unroll
    for (int r = 0; r < 16; ++r) {
      const int o = ob + (r & 3) + 8 * (r >> 2) + 4 * b5;
      float v = acc[mm][r] * alpha[o] + beta[o];
      float sg = v / (1.f + __expf(-v));
      acc[mm][r] = sg;
      if (ob < 128)
        out[(((size_t)(b * 256 + o)) * 64 + h) * 64 + wv] = sg;
    }
  }
  __syncthreads();                        // xs dead -> reuse as ep
  if (mg == 1) {                          // tiles 4,5 hold o in [128,192)
    const int px = rw * 64 + nn * 32 + l31;
#pragma unroll
    for (int mm = 1; mm < 3; ++mm) {
      const int mt = mt0 + mm;            // 4,5
#pragma unroll
      for (int r4 = 0; r4 < 4; ++r4) {
        union { bf16 h4[4]; uint2 u; } pk;
#pragma unroll
        for (int r2 = 0; r2 < 4; ++r2) pk.h4[r2] = (bf16)acc[mm][r4 * 4 + r2];
        *(uint2*)&sm.ep[px * 72 + (mt - 4) * 32 + 8 * r4 + 4 * b5] = pk.u;
      }
    }
  }
  __syncthreads();
#pragma unroll
  for (int p = 0; p < 2; ++p) {
    int id = tid + p * 512;               // 1024 chunks = 128 px x 8
    int c8 = id & 7, px = id >> 3;
    bf16x8 v = *(const bf16x8*)&sm.ep[px * 72 + c8 * 8];
    const int r = px >> 6, wv2 = px & 63;
    *(bf16x8*)&padout[(((size_t)(b * 64 + h0 + r)) * 64 + wv2) * 64 + c8 * 8] = v;
  }
}

// ---------------- conv2/conv3: 16x16x32 template (proven R8/R9 path) -------------
template<int CIN, int NMT, int MM, int C1, bool HASPAD, int TPB, int RB, bool XSWZ>
__global__ __launch_bounds__(TPB, 4)
void conv_k(const bf16* __restrict__ xin,
            const bf16* __restrict__ wpk,
            const float* __restrict__ alpha,
            const float* __restrict__ beta,
            float* __restrict__ out, int chan_off,
            bf16* __restrict__ padout,
            const bf16* __restrict__ zpage) {
  constexpr int NC    = CIN / 32;
  constexpr int NG    = NMT / MM;
  constexpr int RS    = RB + 2;
  constexpr int NCHK  = RS * 66 * 4;
  constexpr int SLOTS = (RB == 2) ? 1088 : 1600;
  constexpr int SUBB  = SLOTS * 16;
  constexpr int P     = (NCHK + TPB - 1) / TPB;
  constexpr int HT    = 64 / RB;
  constexpr int NBLK  = 32 * HT;
  static_assert(NC == 2, "this template path is for CIN=64 layers");

  __shared__ __align__(16) union U {
    char xs[2 * SUBB];
    bf16 ep[RB * 64 * 72];
  } sm;

  const int tid  = threadIdx.x;
  const int wave = tid >> 6;
  const int lane = tid & 63;
  const int q    = lane >> 4;
  const int t16  = lane & 15;
  const int rw   = wave / NG;
  const int mt0  = (wave % NG) * MM;
  const int wg   = (int)blockIdx.x;
  const int wgid = XSWZ ? (wg & 7) * (NBLK / 8) + (wg >> 3) : wg;
  const int b    = wgid / HT;
  const int h0   = (wgid % HT) * RB;

  const bf16* srcp[P];
  int step[P];
#pragma unroll
  for (int p = 0; p < P; ++p) {
    const int id = tid + p * TPB;
    const int c8p = id & 3, rj = id >> 2;
    const int j = rj % 66, r = rj / 66;
    const int hh = h0 + r - 1, ww = j - 1;
    const bool v = (id < NCHK) && ((unsigned)hh < 64u) && ((unsigned)ww < 64u);
    const int c8 = c8p ^ ((j >> 1) & 3);
    srcp[p] = v ? &xin[(((size_t)(b * 64 + hh)) * 64 + ww) * CIN + c8 * 8] : zpage;
    step[p] = v ? 32 : 0;
  }

  int Caddr[3];
#pragma unroll
  for (int kw = 0; kw < 3; ++kw) {
    const int col = t16 + kw;
    Caddr[kw] = rw * 4224 + col * 64 + ((q ^ ((col >> 1) & 3)) << 4);
  }

  char* const lds0 = (char*)&sm.xs[0];

  // prologue: stage BOTH 32-ch sub-chunks (pad-safe via step)
#pragma unroll
  for (int p = 0; p < P; ++p) {
    if ((p + 1) * TPB <= NCHK || p * TPB + wave * 64 < NCHK) {
      GL16(srcp[p],           lds0 +        (p * TPB + wave * 64) * 16);
      GL16(srcp[p] + step[p], lds0 + SUBB + (p * TPB + wave * 64) * 16);
    }
  }
  MEMFENCE();

  bf16x8 aE[MM], aO[MM];
#pragma unroll
  for (int mm = 0; mm < MM; ++mm)
    aE[mm] = *(const bf16x8*)&wpk[((size_t)(mt0 + mm) * 64 + lane) * 8];

  f32x4 acc[4][MM] = {};

  vwait<MM>();                           // ALL GL16s retired; aE in flight
  __builtin_amdgcn_s_barrier();
  __builtin_amdgcn_s_setprio(1);
#pragma unroll
  for (int sub = 0; sub < 2; ++sub) {
    const int ci = sub;
    bf16x8 bb0[4], bb1[4];
#pragma unroll
    for (int nt = 0; nt < 4; ++nt)
      bb0[nt] = *(const bf16x8*)(lds0 + (Caddr[0] + sub * SUBB + nt * 1024));
#pragma unroll
    for (int pos = 0; pos < 9; ++pos) {
      bf16x8* bc = (pos & 1) ? bb1 : bb0;
      bf16x8* bn = (pos & 1) ? bb0 : bb1;
      if (pos < 8) {
        const int kh1 = (pos + 1) / 3, kw1 = (pos + 1) % 3;
#pragma unroll
        for (int nt = 0; nt < 4; ++nt)
          bn[nt] = *(const bf16x8*)(lds0 +
              (Caddr[kw1] + sub * SUBB + nt * 1024 + kh1 * 4224));
      }
      bf16x8* ac = (pos & 1) ? aO : aE;
      bf16x8* an = (pos & 1) ? aE : aO;
      if (pos < 8) {
        const int ksn = (pos + 1) * NC + ci;
#pragma unroll
        for (int mm = 0; mm < MM; ++mm)
          an[mm] = *(const bf16x8*)&wpk[((size_t)(ksn * NMT + mt0 + mm) * 64 + lane) * 8];
      }
#pragma unroll
      for (int nt = 0; nt < 4; ++nt)
#pragma unroll
        for (int mm = 0; mm < MM; ++mm)
          acc[nt][mm] = __builtin_amdgcn_mfma_f32_16x16x32_bf16(ac[mm], bc[nt], acc[nt][mm], 0, 0, 0);
      if (pos == 8 && ci + 1 < NC) {
#pragma unroll
        for (int mm = 0; mm < MM; ++mm)
          aE[mm] = *(const bf16x8*)&wpk[((size_t)((ci + 1) * NMT + mt0 + mm) * 64 + lane) * 8];
      }
    }
  }
  __builtin_amdgcn_s_setprio(0);

  const int h = h0 + rw;
#pragma unroll
  for (int mm = 0; mm < MM; ++mm) {
    const int o0 = (mt0 + mm) * 16 + 4 * q;
    float av[4], bv2[4];
#pragma unroll
    for (int i = 0; i < 4; ++i) { av[i] = alpha[o0 + i]; bv2[i] = beta[o0 + i]; }
#pragma unroll
    for (int nt = 0; nt < 4; ++nt) {
      const int wv = nt * 16 + t16;
#pragma unroll
      for (int i = 0; i < 4; ++i) {
        float v = acc[nt][mm][i] * av[i] + bv2[i];
        float sg = v / (1.f + __expf(-v));
        acc[nt][mm][i] = sg;
        if (o0 < C1)
          out[(((size_t)(b * 256 + chan_off + o0 + i)) * 64 + h) * 64 + wv] = sg;
      }
    }
  }
  if (HASPAD) {
    __syncthreads();
#pragma unroll
    for (int mm = 0; mm < MM; ++mm) {
      const int o0 = (mt0 + mm) * 16 + 4 * q;
      if (o0 >= C1) {
#pragma unroll
        for (int nt = 0; nt < 4; ++nt) {
          const int px = rw * 64 + nt * 16 + t16;
          union { bf16 h4[4]; uint2 u; } pk;
#pragma unroll
          for (int i = 0; i < 4; ++i) pk.h4[i] = (bf16)acc[nt][mm][i];
          *(uint2*)&sm.ep[px * 72 + (o0 - C1)] = pk.u;
        }
      }
    }
    __syncthreads();
    constexpr int EPP = (RB * 64 * 8) / TPB;
#pragma unroll
    for (int p = 0; p < EPP; ++p) {
      int id = tid + p * TPB;
      int c8 = id & 7, px = id >> 3;
      bf16x8 v = *(const bf16x8*)&sm.ep[px * 72 + c8 * 8];
      const int r = px >> 6, wv2 = px & 63;
      *(bf16x8*)&padout[(((size_t)(b * 64 + h0 + r)) * 64 + wv2) * 64 + c8 * 8] = v;
    }
  }
}

extern "C" void kernel_launch(void* const* d_in, const int* in_sizes, int n_in,
                              void* d_out, int out_size, void* d_ws, size_t ws_size,
                              hipStream_t stream) {
  QArgs qa;
  const float* x = (const float*)d_in[0];
  for (int L = 0; L < 5; ++L) {
    qa.w[L]  = (const float*)d_in[1 + 5 * L];
    qa.g[L]  = (const float*)d_in[2 + 5 * L];
    qa.bb[L] = (const float*)d_in[3 + 5 * L];
    qa.m[L]  = (const float*)d_in[4 + 5 * L];
    qa.v[L]  = (const float*)d_in[5 + 5 * L];
  }
  char* p = (char*)d_ws;
  bf16* wpk1 = (bf16*)p; p += (size_t)192 * 2304 * 2;
  bf16* wpk2 = (bf16*)p; p += (size_t)128 * 576 * 2;
  bf16* wpk3 = (bf16*)p; p += (size_t)64 * 576 * 2;
  float* a1 = (float*)p; p += 1024;
  float* b1 = (float*)p; p += 1024;
  float* a2 = (float*)p; p += 1024;
  float* b2 = (float*)p; p += 1024;
  float* a3 = (float*)p; p += 1024;
  float* b3 = (float*)p; p += 1024;
  float* zp = (float*)p; p += 128;                             // 128B zero page
  bf16* xT   = (bf16*)p; p += (size_t)32 * 64 * 64 * 256 * 2;  // 67.1 MB
  bf16* stem = (bf16*)p; p += (size_t)32 * 64 * 64 * 64 * 2;   // 16.8 MB
  bf16* tbuf = xT;                                             // alias: xT dead after stage 1
  qa.wpk[0] = wpk1; qa.wpk[1] = wpk2; qa.wpk[2] = wpk3;
  qa.alpha[0] = a1; qa.alpha[1] = a2; qa.alpha[2] = a3;
  qa.beta[0]  = b1; qa.beta[1]  = b2; qa.beta[2]  = b3;

  prep_k<<<384 + 32 * 64 * 4, 256, 0, stream>>>(qa, x, xT, zp);

  const bf16* zpb = (const bf16*)zp;
  conv1_k<<<1024, 512, 0, stream>>>(xT, wpk1, a1, b1, (float*)d_out, stem, zpb);
  conv_k< 64,  8, 2,  64, true, 1024, 4, true ><<< 512, 1024, 0, stream>>>(stem, wpk2, a2, b2, (float*)d_out, 128, tbuf, zpb);
  conv_k< 64,  4, 2,  64, false, 512, 4, true ><<< 512,  512, 0, stream>>>(tbuf, wpk3, a3, b3, (float*)d_out, 192, nullptr, zpb);
}

// Round 11
// 425.196 us; speedup vs baseline: 1.0569x; 1.0569x over previous
//
#include <hip/hip_runtime.h>
#include <stdint.h>

#define EPSF 1e-5f

typedef __bf16 bf16;
typedef __attribute__((ext_vector_type(8))) __bf16 bf16x8;
typedef __attribute__((ext_vector_type(4))) float f32x4;

// async global->LDS, 16B per lane, dest = wave-uniform base + lane*16 (linear)
#define GL16(src, dst) __builtin_amdgcn_global_load_lds( \
    (const __attribute__((address_space(1))) void*)(src), \
    (__attribute__((address_space(3))) void*)(dst), 16, 0, 0)
// IR+ISA ordering fence for memory ops (pins GL16 issue order vs A-loads/ds_reads)
#define MEMFENCE() asm volatile("" ::: "memory")

// counted vmcnt. Ledger per wait site (R7-derived, R8-verified):
//  - ci==0 (all NC): outstanding = GL16s + MM aE-loads -> vwait<MM> retires ALL
//    GL16s (both sub-buffers for NC==2), keeps aE in flight.
//  - ci>=1 (NC>2): newest 2*MM = pos7 tap8-loads + pos8 next-tap0 loads; vmcnt(2*MM)
//    retires everything older incl. chunk ci's GL16s (issued at top of iter ci-1).
template<int N> __device__ __forceinline__ void vwait() {
  static_assert(N == 1 || N == 2 || N == 3 || N == 4 || N == 6, "unsupported vmcnt");
  if constexpr (N == 1) asm volatile("s_waitcnt vmcnt(1)" ::: "memory");
  else if constexpr (N == 2) asm volatile("s_waitcnt vmcnt(2)" ::: "memory");
  else if constexpr (N == 3) asm volatile("s_waitcnt vmcnt(3)" ::: "memory");
  else if constexpr (N == 4) asm volatile("s_waitcnt vmcnt(4)" ::: "memory");
  else asm volatile("s_waitcnt vmcnt(6)" ::: "memory");
}

// ---------------- fused prep: quant (blocks 0..383) + transpose (384..8575) -----
// quant: median via bitwise order-statistic binary search (MSB->LSB), packed
// 16|16 ranks; BN-fold; MFMA A-fragment prepack (16x16x32 layout, all gemms).
// transpose: NCHW fp32 -> c-minor bf16 xT[b][h][w][256], float4 global loads.
struct QArgs {
  const float* w[5];
  const float* g[5];
  const float* bb[5];
  const float* m[5];
  const float* v[5];
  bf16* wpk[3];
  float* alpha[3];
  float* beta[3];
};

__global__ __launch_bounds__(256)
void prep_k(QArgs qa, const float* __restrict__ x, bf16* __restrict__ xT,
            float* __restrict__ zp) {
  __shared__ int red[2][4];
  __shared__ float tile[64 * 66];
  const int tid = threadIdx.x;
  if (blockIdx.x == 0 && tid < 32) zp[tid] = 0.0f;   // 128B zero page

  if (blockIdx.x < 384) {
    // ---------------- quant branch ----------------
    const int blk = blockIdx.x;
    int layer, o;
    if (blk < 128)      { layer = 0; o = blk; }
    else if (blk < 192) { layer = 1; o = blk - 128; }
    else if (blk < 256) { layer = 2; o = blk - 192; }
    else if (blk < 320) { layer = 3; o = blk - 256; }
    else                { layer = 4; o = blk - 320; }
    const int I_[5]     = {256, 256, 64, 64, 64};
    const int gemm_[5]  = {0, 0, 1, 1, 2};
    const int obase_[5] = {0, 128, 0, 64, 0};
    const int gNMT[3]   = {12, 8, 4};
    const int I = I_[layer];
    const int n = I * 9;                       // 2304 or 576
    const float* w = qa.w[layer] + (size_t)o * n;

    unsigned key[9];
#pragma unroll
    for (int j = 0; j < 9; ++j) key[j] = 0xFFFFFFFFu;   // pad: never < cand
    {
      int c2 = 0;
      for (int i = tid; i < n; i += 256) key[c2++] = __float_as_uint(fabsf(w[i]));
    }

    const int wv = tid >> 6;
    unsigned pfx[2] = {0u, 0u};
    const int rank0 = n / 2 - 1, rank1 = n / 2;
    int pp = 0;
    for (int bit = 31; bit >= 0; --bit) {
      const unsigned c0 = pfx[0] | (1u << bit);
      const unsigned c1 = pfx[1] | (1u << bit);
      int loc = 0;
#pragma unroll
      for (int j = 0; j < 9; ++j)
        loc += (key[j] < c0 ? 1 : 0) + (key[j] < c1 ? 0x10000 : 0);
      loc += __shfl_xor(loc, 32); loc += __shfl_xor(loc, 16);
      loc += __shfl_xor(loc, 8);  loc += __shfl_xor(loc, 4);
      loc += __shfl_xor(loc, 2);  loc += __shfl_xor(loc, 1);
      if ((tid & 63) == 0) red[pp][wv] = loc;
      __syncthreads();
      const int tot = red[pp][0] + red[pp][1] + red[pp][2] + red[pp][3];
      if ((tot & 0xFFFF) <= rank0) pfx[0] = c0;
      if ((tot >> 16)    <= rank1) pfx[1] = c1;
      pp ^= 1;
    }
    const float s =
        fmaxf(0.5f * (__uint_as_float(pfx[0]) + __uint_as_float(pfx[1])), EPSF);

    const int g  = gemm_[layer];
    const int ob = obase_[layer];
    const int NMT = gNMT[g];
    if (tid == 0) {
      float inv = qa.g[layer][o] / sqrtf(qa.v[layer][o] + EPSF);
      qa.alpha[g][ob + o] = s * inv;
      qa.beta[g][ob + o]  = qa.bb[layer][o] - qa.m[layer][o] * inv;
    }
    const int og  = ob + o;
    const int mt  = og >> 4;
    const int l16 = og & 15;
    bf16* wp = qa.wpk[g];
    for (int i = tid; i < n; i += 256) {
      float t = rintf(w[i] / s);
      t = fmaxf(-1.f, fminf(1.f, t));
      int c = i / 9, pos = i % 9;
      int k = pos * I + c;
      int ks = k >> 5, kq = (k >> 3) & 3, jj = k & 7;
      wp[((size_t)((ks * NMT + mt) * 64 + kq * 16 + l16)) * 8 + jj] = (bf16)t;
    }
    return;
  }

  // ---------------- transpose branch ----------------
  const int blk = blockIdx.x - 384;
  const int cg = blk & 3;
  const int h  = (blk >> 2) & 63;
  const int b  = blk >> 8;
  const int w4 = (tid & 15) * 4;
  const int cb = tid >> 4;               // 0..15
#pragma unroll
  for (int p = 0; p < 4; ++p) {
    int c = cb + p * 16;
    const float4 v =
        *(const float4*)&x[(((size_t)(b * 256 + cg * 64 + c)) * 64 + h) * 64 + w4];
    tile[(w4 + 0) * 66 + c] = v.x;
    tile[(w4 + 1) * 66 + c] = v.y;
    tile[(w4 + 2) * 66 + c] = v.z;
    tile[(w4 + 3) * 66 + c] = v.w;
  }
  __syncthreads();
#pragma unroll
  for (int p = 0; p < 2; ++p) {
    int id = tid + p * 256;
    int c8 = id & 7, w2 = id >> 3;
    const float* src = &tile[w2 * 66 + c8 * 8];
    float2 f0 = *(const float2*)(src + 0);
    float2 f1 = *(const float2*)(src + 2);
    float2 f2 = *(const float2*)(src + 4);
    float2 f3 = *(const float2*)(src + 6);
    bf16x8 v;
    v[0] = (bf16)f0.x; v[1] = (bf16)f0.y; v[2] = (bf16)f1.x; v[3] = (bf16)f1.y;
    v[4] = (bf16)f2.x; v[5] = (bf16)f2.y; v[6] = (bf16)f3.x; v[7] = (bf16)f3.y;
    *(bf16x8*)&xT[(((size_t)(b * 64 + h)) * 64 + w2) * 256 + cg * 64 + c8 * 8] = v;
  }
}

// ---------------- implicit-GEMM conv3x3 (pad=1) + fused BN + SiLU ----------------
// R8 structure (best measured): BK=32 per barrier, B-fragment register dbuf one
// tap ahead, A 2-slot ping-pong with cross-barrier tap0, global_load_lds w=16,
// chunk XOR-swizzle on global source + read side (G21). Per-wave tile 48ch x
// 64px (m_w+n_w minimal -> balanced A-L2 / B-LDS traffic; 32x32 variant with
// 96x32 doubled A traffic and 25x'd bank conflicts -> R10 regression).
//   conv1: TPB=512, RB=2 (2 blocks/CU barrier overlap partner)
//   conv2: TPB=1024, RB=4, MM=2
//   conv3: TPB=1024, RB=4, MM=1 (R5-measured ~12us better than 512/4/MM=2)
template<int CIN, int NMT, int MM, int C1, bool HASPAD, int TPB, int RB, bool XSWZ>
__global__ __launch_bounds__(TPB, 4)
void conv_k(const bf16* __restrict__ xin,   // [B][64][64][CIN] c-minor bf16
            const bf16* __restrict__ wpk,
            const float* __restrict__ alpha,
            const float* __restrict__ beta,
            float* __restrict__ out, int chan_off,
            bf16* __restrict__ padout,      // [B][64][64][64] c-minor bf16
            const bf16* __restrict__ zpage) {
  constexpr int NC    = CIN / 32;
  constexpr int NG    = NMT / MM;          // m-groups per row
  constexpr int RS    = RB + 2;            // staged rows incl. halo
  constexpr int NCHK  = RS * 66 * 4;       // live 16B chunks per buffer
  constexpr int SLOTS = (RB == 2) ? 1088 : 1600;  // +guard (wave-granular GL16)
  constexpr int BUFB  = SLOTS * 16;        // buffer stride, bytes
  constexpr int P     = (NCHK + TPB - 1) / TPB;   // staging passes
  constexpr int HT    = 64 / RB;           // h-tiles per image
  constexpr int NBLK  = 32 * HT;

  __shared__ __align__(16) union U {
    bf16 xs[2][SLOTS * 8];
    bf16 ep[RB * 64 * 72];
  } sm;

  const int tid  = threadIdx.x;
  const int wave = tid >> 6;
  const int lane = tid & 63;
  const int q    = lane >> 4;
  const int t16  = lane & 15;
  const int rw   = wave / NG;              // output row within block
  const int mt0  = (wave % NG) * MM;
  const int wg   = (int)blockIdx.x;
  const int wgid = XSWZ ? (wg & 7) * (NBLK / 8) + (wg >> 3) : wg;
  const int b    = wgid / HT;
  const int h0   = (wgid % HT) * RB;

  // staging map: chunk id = (r*66 + j)*4 + c8p ; per-pass ids = tid + p*TPB
  const bf16* srcp[P];
  int step[P];
#pragma unroll
  for (int p = 0; p < P; ++p) {
    const int id = tid + p * TPB;
    const int c8p = id & 3, rj = id >> 2;
    const int j = rj % 66, r = rj / 66;
    const int hh = h0 + r - 1, ww = j - 1;
    const bool v = (id < NCHK) && ((unsigned)hh < 64u) && ((unsigned)ww < 64u);
    const int c8 = c8p ^ ((j >> 1) & 3);          // inverse swizzle on source
    srcp[p] = v ? &xin[(((size_t)(b * 64 + hh)) * 64 + ww) * CIN + c8 * 8] : zpage;
    step[p] = v ? 32 : 0;                          // +32 ch per c-iter, pad lanes pinned
  }

  auto stage = [&](char* base, bool second) {
#pragma unroll
    for (int p = 0; p < P; ++p) {
      if ((p + 1) * TPB <= NCHK || p * TPB + wave * 64 < NCHK)
        GL16(srcp[p] + (second ? step[p] : 0), base + (p * TPB + wave * 64) * 16);
    }
  };

  // B-read base addresses (buf0), one per kw
  int Caddr[3];
#pragma unroll
  for (int kw = 0; kw < 3; ++kw) {
    const int col = t16 + kw;
    Caddr[kw] = rw * 4224 + col * 64 + ((q ^ ((col >> 1) & 3)) << 4);
  }

  char* const lds0 = (char*)&sm.xs[0][0];

  // prologue staging
  stage(lds0, false);
  if constexpr (NC == 2) {
    stage(lds0 + BUFB, true);              // second 32-ch chunk, pad-safe via step
  } else {
#pragma unroll
    for (int p = 0; p < P; ++p) srcp[p] += step[p];
  }
  MEMFENCE();

  // A-fragment 2-slot ping-pong: aE = tap0
  bf16x8 aE[MM], aO[MM];
#pragma unroll
  for (int mm = 0; mm < MM; ++mm)
    aE[mm] = *(const bf16x8*)&wpk[((size_t)(mt0 + mm) * 64 + lane) * 8];

  f32x4 acc[4][MM] = {};
  int tog = BUFB;

  for (int ci = 0; ci < NC; ++ci) {
    if (ci == 0) {
      vwait<MM>();                         // ALL GL16s retired; aE stays in flight
      __builtin_amdgcn_s_barrier();
    } else if constexpr (NC > 2) {
      vwait<2 * MM>();                     // GL16s retired; tap8+next-tap0 in flight
      __builtin_amdgcn_s_barrier();
    }
    if constexpr (NC > 2) {
      if (ci + 1 < NC) {                   // issue next chunk's direct-to-LDS loads
        stage(lds0 + (((ci + 1) & 1) ? BUFB : 0), false);
#pragma unroll
        for (int p = 0; p < P; ++p) srcp[p] += step[p];
      }
    }
    MEMFENCE();                            // GL16 issue pinned before A/B reads
    // B-fragment double buffer: pre-read tap0
    bf16x8 bb0[4], bb1[4];
#pragma unroll
    for (int nt = 0; nt < 4; ++nt)
      bb0[nt] = *(const bf16x8*)(lds0 + (Caddr[0] + nt * 1024));
    __builtin_amdgcn_s_setprio(1);
#pragma unroll
    for (int pos = 0; pos < 9; ++pos) {
      bf16x8* bc = (pos & 1) ? bb1 : bb0;
      bf16x8* bn = (pos & 1) ? bb0 : bb1;
      if (pos < 8) {                       // issue tap pos+1 B-reads first
        const int kh1 = (pos + 1) / 3, kw1 = (pos + 1) % 3;
#pragma unroll
        for (int nt = 0; nt < 4; ++nt)
          bn[nt] = *(const bf16x8*)(lds0 + (Caddr[kw1] + nt * 1024 + kh1 * 4224));
      }
      bf16x8* ac = (pos & 1) ? aO : aE;
      bf16x8* an = (pos & 1) ? aE : aO;
      if (pos < 8) {                       // A prefetch one tap ahead
        const int ksn = (pos + 1) * NC + ci;
#pragma unroll
        for (int mm = 0; mm < MM; ++mm)
          an[mm] = *(const bf16x8*)&wpk[((size_t)(ksn * NMT + mt0 + mm) * 64 + lane) * 8];
      }
#pragma unroll
      for (int nt = 0; nt < 4; ++nt)
#pragma unroll
        for (int mm = 0; mm < MM; ++mm)
          acc[nt][mm] = __builtin_amdgcn_mfma_f32_16x16x32_bf16(ac[mm], bc[nt], acc[nt][mm], 0, 0, 0);
      if (pos == 8 && ci + 1 < NC) {       // next c-iter tap0 AFTER consuming aE
#pragma unroll
        for (int mm = 0; mm < MM; ++mm)
          aE[mm] = *(const bf16x8*)&wpk[((size_t)((ci + 1) * NMT + mt0 + mm) * 64 + lane) * 8];
      }
    }
    __builtin_amdgcn_s_setprio(0);
#pragma unroll
    for (int kw = 0; kw < 3; ++kw) Caddr[kw] += tog;   // buffer toggle
    tog = -tog;
  }

  // epilogue: BN + SiLU; fp32 NCHW stores for o < C1
  const int h = h0 + rw;
#pragma unroll
  for (int mm = 0; mm < MM; ++mm) {
    const int o0 = (mt0 + mm) * 16 + 4 * q;
    float av[4], bv2[4];
#pragma unroll
    for (int i = 0; i < 4; ++i) { av[i] = alpha[o0 + i]; bv2[i] = beta[o0 + i]; }
#pragma unroll
    for (int nt = 0; nt < 4; ++nt) {
      const int wv = nt * 16 + t16;
#pragma unroll
      for (int i = 0; i < 4; ++i) {
        float v = acc[nt][mm][i] * av[i] + bv2[i];
        float sg = v / (1.f + __expf(-v));
        acc[nt][mm][i] = sg;
        if (o0 < C1)
          out[(((size_t)(b * 256 + chan_off + o0 + i)) * 64 + h) * 64 + wv] = sg;
      }
    }
  }
  if (HASPAD) {
    __syncthreads();                       // full sync: xs dead -> reuse as ep
#pragma unroll
    for (int mm = 0; mm < MM; ++mm) {
      const int o0 = (mt0 + mm) * 16 + 4 * q;
      if (o0 >= C1) {
#pragma unroll
        for (int nt = 0; nt < 4; ++nt) {
          const int px = rw * 64 + nt * 16 + t16;
          union { bf16 h4[4]; uint2 u; } pk;
#pragma unroll
          for (int i = 0; i < 4; ++i) pk.h4[i] = (bf16)acc[nt][mm][i];
          *(uint2*)&sm.ep[px * 72 + (o0 - C1)] = pk.u;
        }
      }
    }
    __syncthreads();
    constexpr int EPP = (RB * 64 * 8) / TPB;
#pragma unroll
    for (int p = 0; p < EPP; ++p) {
      int id = tid + p * TPB;              // RB*64*8 chunks = RB*64 px x 8
      int c8 = id & 7, px = id >> 3;
      bf16x8 v = *(const bf16x8*)&sm.ep[px * 72 + c8 * 8];
      const int r = px >> 6, wv2 = px & 63;
      *(bf16x8*)&padout[(((size_t)(b * 64 + h0 + r)) * 64 + wv2) * 64 + c8 * 8] = v;
    }
  }
}

extern "C" void kernel_launch(void* const* d_in, const int* in_sizes, int n_in,
                              void* d_out, int out_size, void* d_ws, size_t ws_size,
                              hipStream_t stream) {
  QArgs qa;
  const float* x = (const float*)d_in[0];
  for (int L = 0; L < 5; ++L) {
    qa.w[L]  = (const float*)d_in[1 + 5 * L];
    qa.g[L]  = (const float*)d_in[2 + 5 * L];
    qa.bb[L] = (const float*)d_in[3 + 5 * L];
    qa.m[L]  = (const float*)d_in[4 + 5 * L];
    qa.v[L]  = (const float*)d_in[5 + 5 * L];
  }
  char* p = (char*)d_ws;
  bf16* wpk1 = (bf16*)p; p += (size_t)192 * 2304 * 2;
  bf16* wpk2 = (bf16*)p; p += (size_t)128 * 576 * 2;
  bf16* wpk3 = (bf16*)p; p += (size_t)64 * 576 * 2;
  float* a1 = (float*)p; p += 1024;
  float* b1 = (float*)p; p += 1024;
  float* a2 = (float*)p; p += 1024;
  float* b2 = (float*)p; p += 1024;
  float* a3 = (float*)p; p += 1024;
  float* b3 = (float*)p; p += 1024;
  float* zp = (float*)p; p += 128;                             // 128B zero page
  bf16* xT   = (bf16*)p; p += (size_t)32 * 64 * 64 * 256 * 2;  // 67.1 MB
  bf16* stem = (bf16*)p; p += (size_t)32 * 64 * 64 * 64 * 2;   // 16.8 MB
  bf16* tbuf = xT;                                             // alias: xT dead after stage 1
  qa.wpk[0] = wpk1; qa.wpk[1] = wpk2; qa.wpk[2] = wpk3;
  qa.alpha[0] = a1; qa.alpha[1] = a2; qa.alpha[2] = a3;
  qa.beta[0]  = b1; qa.beta[1]  = b2; qa.beta[2]  = b3;

  prep_k<<<384 + 32 * 64 * 4, 256, 0, stream>>>(qa, x, xT, zp);

  const bf16* zpb = (const bf16*)zp;
  conv_k<256, 12, 3, 128, true,  512, 2, false><<<1024,  512, 0, stream>>>(xT,   wpk1, a1, b1, (float*)d_out, 0,   stem, zpb);
  conv_k< 64,  8, 2,  64, true, 1024, 4, true ><<< 512, 1024, 0, stream>>>(stem, wpk2, a2, b2, (float*)d_out, 128, tbuf, zpb);
  conv_k< 64,  4, 1,  64, false, 1024, 4, true ><<< 512, 1024, 0, stream>>>(tbuf, wpk3, a3, b3, (float*)d_out, 192, nullptr, zpb);
}

// Round 12
// 423.091 us; speedup vs baseline: 1.0622x; 1.0050x over previous
//
#include <hip/hip_runtime.h>
#include <stdint.h>

#define EPSF 1e-5f

typedef __bf16 bf16;
typedef __attribute__((ext_vector_type(8))) __bf16 bf16x8;
typedef __attribute__((ext_vector_type(4))) float f32x4;

// async global->LDS, 16B per lane, dest = wave-uniform base + lane*16 (linear)
#define GL16(src, dst) __builtin_amdgcn_global_load_lds( \
    (const __attribute__((address_space(1))) void*)(src), \
    (__attribute__((address_space(3))) void*)(dst), 16, 0, 0)
// IR+ISA ordering fence for memory ops (pins GL16 issue order vs A-loads/ds_reads)
#define MEMFENCE() asm volatile("" ::: "memory")

// counted vmcnt. Ledger per wait site (R7-derived, R8-verified):
//  - ci==0 (all NC): outstanding = GL16s + MM aE-loads -> vwait<MM> retires ALL
//    GL16s (both sub-buffers for NC==2), keeps aE in flight.
//  - ci>=1 (NC>2): newest 2*MM = pos7 tap8-loads + pos8 next-tap0 loads; vmcnt(2*MM)
//    retires everything older incl. chunk ci's GL16s (issued at top of iter ci-1).
template<int N> __device__ __forceinline__ void vwait() {
  static_assert(N == 1 || N == 2 || N == 3 || N == 4 || N == 6, "unsupported vmcnt");
  if constexpr (N == 1) asm volatile("s_waitcnt vmcnt(1)" ::: "memory");
  else if constexpr (N == 2) asm volatile("s_waitcnt vmcnt(2)" ::: "memory");
  else if constexpr (N == 3) asm volatile("s_waitcnt vmcnt(3)" ::: "memory");
  else if constexpr (N == 4) asm volatile("s_waitcnt vmcnt(4)" ::: "memory");
  else asm volatile("s_waitcnt vmcnt(6)" ::: "memory");
}

// ---------------- fused prep: quant (blocks 0..383) + transpose (384..8575) -----
struct QArgs {
  const float* w[5];
  const float* g[5];
  const float* bb[5];
  const float* m[5];
  const float* v[5];
  bf16* wpk[3];
  float* alpha[3];
  float* beta[3];
};

__global__ __launch_bounds__(256)
void prep_k(QArgs qa, const float* __restrict__ x, bf16* __restrict__ xT,
            float* __restrict__ zp) {
  __shared__ int red[2][4];
  __shared__ float tile[64 * 66];
  const int tid = threadIdx.x;
  if (blockIdx.x == 0 && tid < 32) zp[tid] = 0.0f;   // 128B zero page

  if (blockIdx.x < 384) {
    // ---------------- quant branch ----------------
    const int blk = blockIdx.x;
    int layer, o;
    if (blk < 128)      { layer = 0; o = blk; }
    else if (blk < 192) { layer = 1; o = blk - 128; }
    else if (blk < 256) { layer = 2; o = blk - 192; }
    else if (blk < 320) { layer = 3; o = blk - 256; }
    else                { layer = 4; o = blk - 320; }
    const int I_[5]     = {256, 256, 64, 64, 64};
    const int gemm_[5]  = {0, 0, 1, 1, 2};
    const int obase_[5] = {0, 128, 0, 64, 0};
    const int gNMT[3]   = {12, 8, 4};
    const int I = I_[layer];
    const int n = I * 9;                       // 2304 or 576
    const float* w = qa.w[layer] + (size_t)o * n;

    unsigned key[9];
#pragma unroll
    for (int j = 0; j < 9; ++j) key[j] = 0xFFFFFFFFu;   // pad: never < cand
    {
      int c2 = 0;
      for (int i = tid; i < n; i += 256) key[c2++] = __float_as_uint(fabsf(w[i]));
    }

    const int wv = tid >> 6;
    unsigned pfx[2] = {0u, 0u};
    const int rank0 = n / 2 - 1, rank1 = n / 2;
    int pp = 0;
    for (int bit = 31; bit >= 0; --bit) {
      const unsigned c0 = pfx[0] | (1u << bit);
      const unsigned c1 = pfx[1] | (1u << bit);
      int loc = 0;
#pragma unroll
      for (int j = 0; j < 9; ++j)
        loc += (key[j] < c0 ? 1 : 0) + (key[j] < c1 ? 0x10000 : 0);
      loc += __shfl_xor(loc, 32); loc += __shfl_xor(loc, 16);
      loc += __shfl_xor(loc, 8);  loc += __shfl_xor(loc, 4);
      loc += __shfl_xor(loc, 2);  loc += __shfl_xor(loc, 1);
      if ((tid & 63) == 0) red[pp][wv] = loc;
      __syncthreads();
      const int tot = red[pp][0] + red[pp][1] + red[pp][2] + red[pp][3];
      if ((tot & 0xFFFF) <= rank0) pfx[0] = c0;
      if ((tot >> 16)    <= rank1) pfx[1] = c1;
      pp ^= 1;
    }
    const float s =
        fmaxf(0.5f * (__uint_as_float(pfx[0]) + __uint_as_float(pfx[1])), EPSF);

    const int g  = gemm_[layer];
    const int ob = obase_[layer];
    const int NMT = gNMT[g];
    if (tid == 0) {
      float inv = qa.g[layer][o] / sqrtf(qa.v[layer][o] + EPSF);
      qa.alpha[g][ob + o] = s * inv;
      qa.beta[g][ob + o]  = qa.bb[layer][o] - qa.m[layer][o] * inv;
    }
    const int og  = ob + o;
    const int mt  = og >> 4;
    const int l16 = og & 15;
    bf16* wp = qa.wpk[g];
    for (int i = tid; i < n; i += 256) {
      float t = rintf(w[i] / s);
      t = fmaxf(-1.f, fminf(1.f, t));
      int c = i / 9, pos = i % 9;
      int k = pos * I + c;
      int ks = k >> 5, kq = (k >> 3) & 3, jj = k & 7;
      wp[((size_t)((ks * NMT + mt) * 64 + kq * 16 + l16)) * 8 + jj] = (bf16)t;
    }
    return;
  }

  // ---------------- transpose branch ----------------
  const int blk = blockIdx.x - 384;
  const int cg = blk & 3;
  const int h  = (blk >> 2) & 63;
  const int b  = blk >> 8;
  const int w4 = (tid & 15) * 4;
  const int cb = tid >> 4;               // 0..15
#pragma unroll
  for (int p = 0; p < 4; ++p) {
    int c = cb + p * 16;
    const float4 v =
        *(const float4*)&x[(((size_t)(b * 256 + cg * 64 + c)) * 64 + h) * 64 + w4];
    tile[(w4 + 0) * 66 + c] = v.x;
    tile[(w4 + 1) * 66 + c] = v.y;
    tile[(w4 + 2) * 66 + c] = v.z;
    tile[(w4 + 3) * 66 + c] = v.w;
  }
  __syncthreads();
#pragma unroll
  for (int p = 0; p < 2; ++p) {
    int id = tid + p * 256;
    int c8 = id & 7, w2 = id >> 3;
    const float* src = &tile[w2 * 66 + c8 * 8];
    float2 f0 = *(const float2*)(src + 0);
    float2 f1 = *(const float2*)(src + 2);
    float2 f2 = *(const float2*)(src + 4);
    float2 f3 = *(const float2*)(src + 6);
    bf16x8 v;
    v[0] = (bf16)f0.x; v[1] = (bf16)f0.y; v[2] = (bf16)f1.x; v[3] = (bf16)f1.y;
    v[4] = (bf16)f2.x; v[5] = (bf16)f2.y; v[6] = (bf16)f3.x; v[7] = (bf16)f3.y;
    *(bf16x8*)&xT[(((size_t)(b * 64 + h)) * 64 + w2) * 256 + cg * 64 + c8 * 8] = v;
  }
}

// ---------------- implicit-GEMM conv3x3 (pad=1) + fused BN + SiLU ----------------
// R8 inner loop (best measured). Geometry per layer:
//   conv1: TPB=256, RB=1 -> 4-wave blocks, 4 barrier domains/CU, 1 wave/SIMD
//          each: when one domain drains at barrier+vmcnt, 3 others feed the
//          MFMA pipe (R5 showed domain count is the live lever; per-wave work
//          and per-CU A-traffic unchanged).
//   conv2: TPB=1024, RB=4, MM=2 (R5/R8 measured best)
//   conv3: TPB=512,  RB=4, MM=2 (R8 vs R11 cross-run A/B: 7.5us better than
//          1024/MM=1)
template<int CIN, int NMT, int MM, int C1, bool HASPAD, int TPB, int RB, bool XSWZ>
__global__ __launch_bounds__(TPB, 4)
void conv_k(const bf16* __restrict__ xin,   // [B][64][64][CIN] c-minor bf16
            const bf16* __restrict__ wpk,
            const float* __restrict__ alpha,
            const float* __restrict__ beta,
            float* __restrict__ out, int chan_off,
            bf16* __restrict__ padout,      // [B][64][64][64] c-minor bf16
            const bf16* __restrict__ zpage) {
  constexpr int NC    = CIN / 32;
  constexpr int NG    = NMT / MM;          // m-groups per row
  constexpr int RS    = RB + 2;            // staged rows incl. halo
  constexpr int NCHK  = RS * 66 * 4;       // live 16B chunks per buffer
  constexpr int SLOTS = ((NCHK + 63) / 64) * 64;  // +guard (wave-granular GL16)
  constexpr int BUFB  = SLOTS * 16;        // buffer stride, bytes
  constexpr int P     = (NCHK + TPB - 1) / TPB;   // staging passes
  constexpr int HT    = 64 / RB;           // h-tiles per image
  constexpr int NBLK  = 32 * HT;

  __shared__ __align__(16) union U {
    bf16 xs[2][SLOTS * 8];
    bf16 ep[RB * 64 * 72];
  } sm;

  const int tid  = threadIdx.x;
  const int wave = tid >> 6;
  const int lane = tid & 63;
  const int q    = lane >> 4;
  const int t16  = lane & 15;
  const int rw   = wave / NG;              // output row within block
  const int mt0  = (wave % NG) * MM;
  const int wg   = (int)blockIdx.x;
  const int wgid = XSWZ ? (wg & 7) * (NBLK / 8) + (wg >> 3) : wg;
  const int b    = wgid / HT;
  const int h0   = (wgid % HT) * RB;

  // staging map: chunk id = (r*66 + j)*4 + c8p ; per-pass ids = tid + p*TPB
  const bf16* srcp[P];
  int step[P];
#pragma unroll
  for (int p = 0; p < P; ++p) {
    const int id = tid + p * TPB;
    const int c8p = id & 3, rj = id >> 2;
    const int j = rj % 66, r = rj / 66;
    const int hh = h0 + r - 1, ww = j - 1;
    const bool v = (id < NCHK) && ((unsigned)hh < 64u) && ((unsigned)ww < 64u);
    const int c8 = c8p ^ ((j >> 1) & 3);          // inverse swizzle on source
    srcp[p] = v ? &xin[(((size_t)(b * 64 + hh)) * 64 + ww) * CIN + c8 * 8] : zpage;
    step[p] = v ? 32 : 0;                          // +32 ch per c-iter, pad lanes pinned
  }

  auto stage = [&](char* base, bool second) {
#pragma unroll
    for (int p = 0; p < P; ++p) {
      if ((p + 1) * TPB <= NCHK || p * TPB + wave * 64 < NCHK)
        GL16(srcp[p] + (second ? step[p] : 0), base + (p * TPB + wave * 64) * 16);
    }
  };

  // B-read base addresses (buf0), one per kw
  int Caddr[3];
#pragma unroll
  for (int kw = 0; kw < 3; ++kw) {
    const int col = t16 + kw;
    Caddr[kw] = rw * 4224 + col * 64 + ((q ^ ((col >> 1) & 3)) << 4);
  }

  char* const lds0 = (char*)&sm.xs[0][0];

  // prologue staging
  stage(lds0, false);
  if constexpr (NC == 2) {
    stage(lds0 + BUFB, true);              // second 32-ch chunk, pad-safe via step
  } else {
#pragma unroll
    for (int p = 0; p < P; ++p) srcp[p] += step[p];
  }
  MEMFENCE();

  // A-fragment 2-slot ping-pong: aE = tap0
  bf16x8 aE[MM], aO[MM];
#pragma unroll
  for (int mm = 0; mm < MM; ++mm)
    aE[mm] = *(const bf16x8*)&wpk[((size_t)(mt0 + mm) * 64 + lane) * 8];

  f32x4 acc[4][MM] = {};
  int tog = BUFB;

  for (int ci = 0; ci < NC; ++ci) {
    if (ci == 0) {
      vwait<MM>();                         // ALL GL16s retired; aE stays in flight
      __builtin_amdgcn_s_barrier();
    } else if constexpr (NC > 2) {
      vwait<2 * MM>();                     // GL16s retired; tap8+next-tap0 in flight
      __builtin_amdgcn_s_barrier();
    }
    if constexpr (NC > 2) {
      if (ci + 1 < NC) {                   // issue next chunk's direct-to-LDS loads
        stage(lds0 + (((ci + 1) & 1) ? BUFB : 0), false);
#pragma unroll
        for (int p = 0; p < P; ++p) srcp[p] += step[p];
      }
    }
    MEMFENCE();                            // GL16 issue pinned before A/B reads
    // B-fragment double buffer: pre-read tap0
    bf16x8 bb0[4], bb1[4];
#pragma unroll
    for (int nt = 0; nt < 4; ++nt)
      bb0[nt] = *(const bf16x8*)(lds0 + (Caddr[0] + nt * 1024));
    __builtin_amdgcn_s_setprio(1);
#pragma unroll
    for (int pos = 0; pos < 9; ++pos) {
      bf16x8* bc = (pos & 1) ? bb1 : bb0;
      bf16x8* bn = (pos & 1) ? bb0 : bb1;
      if (pos < 8) {                       // issue tap pos+1 B-reads first
        const int kh1 = (pos + 1) / 3, kw1 = (pos + 1) % 3;
#pragma unroll
        for (int nt = 0; nt < 4; ++nt)
          bn[nt] = *(const bf16x8*)(lds0 + (Caddr[kw1] + nt * 1024 + kh1 * 4224));
      }
      bf16x8* ac = (pos & 1) ? aO : aE;
      bf16x8* an = (pos & 1) ? aE : aO;
      if (pos < 8) {                       // A prefetch one tap ahead
        const int ksn = (pos + 1) * NC + ci;
#pragma unroll
        for (int mm = 0; mm < MM; ++mm)
          an[mm] = *(const bf16x8*)&wpk[((size_t)(ksn * NMT + mt0 + mm) * 64 + lane) * 8];
      }
#pragma unroll
      for (int nt = 0; nt < 4; ++nt)
#pragma unroll
        for (int mm = 0; mm < MM; ++mm)
          acc[nt][mm] = __builtin_amdgcn_mfma_f32_16x16x32_bf16(ac[mm], bc[nt], acc[nt][mm], 0, 0, 0);
      if (pos == 8 && ci + 1 < NC) {       // next c-iter tap0 AFTER consuming aE
#pragma unroll
        for (int mm = 0; mm < MM; ++mm)
          aE[mm] = *(const bf16x8*)&wpk[((size_t)((ci + 1) * NMT + mt0 + mm) * 64 + lane) * 8];
      }
    }
    __builtin_amdgcn_s_setprio(0);
#pragma unroll
    for (int kw = 0; kw < 3; ++kw) Caddr[kw] += tog;   // buffer toggle
    tog = -tog;
  }

  // epilogue: BN + SiLU; fp32 NCHW stores for o < C1
  const int h = h0 + rw;
#pragma unroll
  for (int mm = 0; mm < MM; ++mm) {
    const int o0 = (mt0 + mm) * 16 + 4 * q;
    float av[4], bv2[4];
#pragma unroll
    for (int i = 0; i < 4; ++i) { av[i] = alpha[o0 + i]; bv2[i] = beta[o0 + i]; }
#pragma unroll
    for (int nt = 0; nt < 4; ++nt) {
      const int wv = nt * 16 + t16;
#pragma unroll
      for (int i = 0; i < 4; ++i) {
        float v = acc[nt][mm][i] * av[i] + bv2[i];
        float sg = v / (1.f + __expf(-v));
        acc[nt][mm][i] = sg;
        if (o0 < C1)
          out[(((size_t)(b * 256 + chan_off + o0 + i)) * 64 + h) * 64 + wv] = sg;
      }
    }
  }
  if (HASPAD) {
    __syncthreads();                       // full sync: xs dead -> reuse as ep
#pragma unroll
    for (int mm = 0; mm < MM; ++mm) {
      const int o0 = (mt0 + mm) * 16 + 4 * q;
      if (o0 >= C1) {
#pragma unroll
        for (int nt = 0; nt < 4; ++nt) {
          const int px = rw * 64 + nt * 16 + t16;
          union { bf16 h4[4]; uint2 u; } pk;
#pragma unroll
          for (int i = 0; i < 4; ++i) pk.h4[i] = (bf16)acc[nt][mm][i];
          *(uint2*)&sm.ep[px * 72 + (o0 - C1)] = pk.u;
        }
      }
    }
    __syncthreads();
    constexpr int EPP = (RB * 64 * 8) / TPB;
#pragma unroll
    for (int p = 0; p < EPP; ++p) {
      int id = tid + p * TPB;              // RB*64*8 chunks = RB*64 px x 8
      int c8 = id & 7, px = id >> 3;
      bf16x8 v = *(const bf16x8*)&sm.ep[px * 72 + c8 * 8];
      const int r = px >> 6, wv2 = px & 63;
      *(bf16x8*)&padout[(((size_t)(b * 64 + h0 + r)) * 64 + wv2) * 64 + c8 * 8] = v;
    }
  }
}

extern "C" void kernel_launch(void* const* d_in, const int* in_sizes, int n_in,
                              void* d_out, int out_size, void* d_ws, size_t ws_size,
                              hipStream_t stream) {
  QArgs qa;
  const float* x = (const float*)d_in[0];
  for (int L = 0; L < 5; ++L) {
    qa.w[L]  = (const float*)d_in[1 + 5 * L];
    qa.g[L]  = (const float*)d_in[2 + 5 * L];
    qa.bb[L] = (const float*)d_in[3 + 5 * L];
    qa.m[L]  = (const float*)d_in[4 + 5 * L];
    qa.v[L]  = (const float*)d_in[5 + 5 * L];
  }
  char* p = (char*)d_ws;
  bf16* wpk1 = (bf16*)p; p += (size_t)192 * 2304 * 2;
  bf16* wpk2 = (bf16*)p; p += (size_t)128 * 576 * 2;
  bf16* wpk3 = (bf16*)p; p += (size_t)64 * 576 * 2;
  float* a1 = (float*)p; p += 1024;
  float* b1 = (float*)p; p += 1024;
  float* a2 = (float*)p; p += 1024;
  float* b2 = (float*)p; p += 1024;
  float* a3 = (float*)p; p += 1024;
  float* b3 = (float*)p; p += 1024;
  float* zp = (float*)p; p += 128;                             // 128B zero page
  bf16* xT   = (bf16*)p; p += (size_t)32 * 64 * 64 * 256 * 2;  // 67.1 MB
  bf16* stem = (bf16*)p; p += (size_t)32 * 64 * 64 * 64 * 2;   // 16.8 MB
  bf16* tbuf = xT;                                             // alias: xT dead after stage 1
  qa.wpk[0] = wpk1; qa.wpk[1] = wpk2; qa.wpk[2] = wpk3;
  qa.alpha[0] = a1; qa.alpha[1] = a2; qa.alpha[2] = a3;
  qa.beta[0]  = b1; qa.beta[1]  = b2; qa.beta[2]  = b3;

  prep_k<<<384 + 32 * 64 * 4, 256, 0, stream>>>(qa, x, xT, zp);

  const bf16* zpb = (const bf16*)zp;
  conv_k<256, 12, 3, 128, true,  256, 1, false><<<2048,  256, 0, stream>>>(xT,   wpk1, a1, b1, (float*)d_out, 0,   stem, zpb);
  conv_k< 64,  8, 2,  64, true, 1024, 4, true ><<< 512, 1024, 0, stream>>>(stem, wpk2, a2, b2, (float*)d_out, 128, tbuf, zpb);
  conv_k< 64,  4, 2,  64, false, 512, 4, true ><<< 512,  512, 0, stream>>>(tbuf, wpk3, a3, b3, (float*)d_out, 192, nullptr, zpb);
}

// Round 13
// 422.651 us; speedup vs baseline: 1.0633x; 1.0010x over previous
//
#include <hip/hip_runtime.h>
#include <stdint.h>

#define EPSF 1e-5f

typedef __bf16 bf16;
typedef __attribute__((ext_vector_type(8))) __bf16 bf16x8;
typedef __attribute__((ext_vector_type(4))) float f32x4;

// async global->LDS, 16B per lane, dest = wave-uniform base + lane*16 (linear)
#define GL16(src, dst) __builtin_amdgcn_global_load_lds( \
    (const __attribute__((address_space(1))) void*)(src), \
    (__attribute__((address_space(3))) void*)(dst), 16, 0, 0)
// IR+ISA ordering fence for memory ops (pins GL16 issue order vs A-loads/ds_reads)
#define MEMFENCE() asm volatile("" ::: "memory")

// counted vmcnt. Ledger per wait site (R7-derived, R8-verified; R13: NC==2 now
// uses the pipelined path):
//  - ci==0 (all NC): outstanding = chunk0 GL16s + MM aE-loads -> vwait<MM>
//    retires ALL chunk0 GL16s, keeps aE in flight.
//  - ci>=1: newest 2*MM = pos7 tap8-loads + pos8 next-tap0 loads; chunk ci's
//    GL16s were issued at the top of iter ci-1 (older) -> vwait<2*MM> retires them.
template<int N> __device__ __forceinline__ void vwait() {
  static_assert(N == 1 || N == 2 || N == 3 || N == 4 || N == 6, "unsupported vmcnt");
  if constexpr (N == 1) asm volatile("s_waitcnt vmcnt(1)" ::: "memory");
  else if constexpr (N == 2) asm volatile("s_waitcnt vmcnt(2)" ::: "memory");
  else if constexpr (N == 3) asm volatile("s_waitcnt vmcnt(3)" ::: "memory");
  else if constexpr (N == 4) asm volatile("s_waitcnt vmcnt(4)" ::: "memory");
  else asm volatile("s_waitcnt vmcnt(6)" ::: "memory");
}

// ---------------- fused prep: quant (blocks 0..383) + transpose (384..8575) -----
struct QArgs {
  const float* w[5];
  const float* g[5];
  const float* bb[5];
  const float* m[5];
  const float* v[5];
  bf16* wpk[3];
  float* alpha[3];
  float* beta[3];
};

__global__ __launch_bounds__(256)
void prep_k(QArgs qa, const float* __restrict__ x, bf16* __restrict__ xT,
            float* __restrict__ zp) {
  __shared__ int red[2][4];
  __shared__ float tile[64 * 66];
  const int tid = threadIdx.x;
  if (blockIdx.x == 0 && tid < 32) zp[tid] = 0.0f;   // 128B zero page

  if (blockIdx.x < 384) {
    // ---------------- quant branch ----------------
    const int blk = blockIdx.x;
    int layer, o;
    if (blk < 128)      { layer = 0; o = blk; }
    else if (blk < 192) { layer = 1; o = blk - 128; }
    else if (blk < 256) { layer = 2; o = blk - 192; }
    else if (blk < 320) { layer = 3; o = blk - 256; }
    else                { layer = 4; o = blk - 320; }
    const int I_[5]     = {256, 256, 64, 64, 64};
    const int gemm_[5]  = {0, 0, 1, 1, 2};
    const int obase_[5] = {0, 128, 0, 64, 0};
    const int gNMT[3]   = {12, 8, 4};
    const int I = I_[layer];
    const int n = I * 9;                       // 2304 or 576
    const float* w = qa.w[layer] + (size_t)o * n;

    unsigned key[9];
#pragma unroll
    for (int j = 0; j < 9; ++j) key[j] = 0xFFFFFFFFu;   // pad: never < cand
    {
      int c2 = 0;
      for (int i = tid; i < n; i += 256) key[c2++] = __float_as_uint(fabsf(w[i]));
    }

    const int wv = tid >> 6;
    unsigned pfx[2] = {0u, 0u};
    const int rank0 = n / 2 - 1, rank1 = n / 2;
    int pp = 0;
    for (int bit = 31; bit >= 0; --bit) {
      const unsigned c0 = pfx[0] | (1u << bit);
      const unsigned c1 = pfx[1] | (1u << bit);
      int loc = 0;
#pragma unroll
      for (int j = 0; j < 9; ++j)
        loc += (key[j] < c0 ? 1 : 0) + (key[j] < c1 ? 0x10000 : 0);
      loc += __shfl_xor(loc, 32); loc += __shfl_xor(loc, 16);
      loc += __shfl_xor(loc, 8);  loc += __shfl_xor(loc, 4);
      loc += __shfl_xor(loc, 2);  loc += __shfl_xor(loc, 1);
      if ((tid & 63) == 0) red[pp][wv] = loc;
      __syncthreads();
      const int tot = red[pp][0] + red[pp][1] + red[pp][2] + red[pp][3];
      if ((tot & 0xFFFF) <= rank0) pfx[0] = c0;
      if ((tot >> 16)    <= rank1) pfx[1] = c1;
      pp ^= 1;
    }
    const float s =
        fmaxf(0.5f * (__uint_as_float(pfx[0]) + __uint_as_float(pfx[1])), EPSF);

    const int g  = gemm_[layer];
    const int ob = obase_[layer];
    const int NMT = gNMT[g];
    if (tid == 0) {
      float inv = qa.g[layer][o] / sqrtf(qa.v[layer][o] + EPSF);
      qa.alpha[g][ob + o] = s * inv;
      qa.beta[g][ob + o]  = qa.bb[layer][o] - qa.m[layer][o] * inv;
    }
    const int og  = ob + o;
    const int mt  = og >> 4;
    const int l16 = og & 15;
    bf16* wp = qa.wpk[g];
    for (int i = tid; i < n; i += 256) {
      float t = rintf(w[i] / s);
      t = fmaxf(-1.f, fminf(1.f, t));
      int c = i / 9, pos = i % 9;
      int k = pos * I + c;
      int ks = k >> 5, kq = (k >> 3) & 3, jj = k & 7;
      wp[((size_t)((ks * NMT + mt) * 64 + kq * 16 + l16)) * 8 + jj] = (bf16)t;
    }
    return;
  }

  // ---------------- transpose branch ----------------
  const int blk = blockIdx.x - 384;
  const int cg = blk & 3;
  const int h  = (blk >> 2) & 63;
  const int b  = blk >> 8;
  const int w4 = (tid & 15) * 4;
  const int cb = tid >> 4;               // 0..15
#pragma unroll
  for (int p = 0; p < 4; ++p) {
    int c = cb + p * 16;
    const float4 v =
        *(const float4*)&x[(((size_t)(b * 256 + cg * 64 + c)) * 64 + h) * 64 + w4];
    tile[(w4 + 0) * 66 + c] = v.x;
    tile[(w4 + 1) * 66 + c] = v.y;
    tile[(w4 + 2) * 66 + c] = v.z;
    tile[(w4 + 3) * 66 + c] = v.w;
  }
  __syncthreads();
#pragma unroll
  for (int p = 0; p < 2; ++p) {
    int id = tid + p * 256;
    int c8 = id & 7, w2 = id >> 3;
    const float* src = &tile[w2 * 66 + c8 * 8];
    float2 f0 = *(const float2*)(src + 0);
    float2 f1 = *(const float2*)(src + 2);
    float2 f2 = *(const float2*)(src + 4);
    float2 f3 = *(const float2*)(src + 6);
    bf16x8 v;
    v[0] = (bf16)f0.x; v[1] = (bf16)f0.y; v[2] = (bf16)f1.x; v[3] = (bf16)f1.y;
    v[4] = (bf16)f2.x; v[5] = (bf16)f2.y; v[6] = (bf16)f3.x; v[7] = (bf16)f3.y;
    *(bf16x8*)&xT[(((size_t)(b * 64 + h)) * 64 + w2) * 256 + cg * 64 + c8 * 8] = v;
  }
}

// ---------------- implicit-GEMM conv3x3 (pad=1) + fused BN + SiLU ----------------
// R8 structure (best measured; conv1 ceiling for this structure established over
// R2-R12: MfmaUtil pinned ~46% against 7 schedule/shape/occupancy interventions).
//   conv1: TPB=512, RB=2 (2 blocks/CU barrier overlap partner)
//   conv2: TPB=1024, RB=4, MM=2
//   conv3: TPB=512,  RB=4, MM=2 (R8-vs-R11 A/B: beats 1024/MM=1 by ~7.5us)
// R13: NC==2 layers now use the pipelined staging path too (stage sub1 UNDER
// sub0's MFMA phase instead of stalling on both up front).
template<int CIN, int NMT, int MM, int C1, bool HASPAD, int TPB, int RB, bool XSWZ>
__global__ __launch_bounds__(TPB, 4)
void conv_k(const bf16* __restrict__ xin,   // [B][64][64][CIN] c-minor bf16
            const bf16* __restrict__ wpk,
            const float* __restrict__ alpha,
            const float* __restrict__ beta,
            float* __restrict__ out, int chan_off,
            bf16* __restrict__ padout,      // [B][64][64][64] c-minor bf16
            const bf16* __restrict__ zpage) {
  constexpr int NC    = CIN / 32;
  constexpr int NG    = NMT / MM;          // m-groups per row
  constexpr int RS    = RB + 2;            // staged rows incl. halo
  constexpr int NCHK  = RS * 66 * 4;       // live 16B chunks per buffer
  constexpr int SLOTS = (RB == 2) ? 1088 : 1600;  // +guard (wave-granular GL16)
  constexpr int BUFB  = SLOTS * 16;        // buffer stride, bytes
  constexpr int P     = (NCHK + TPB - 1) / TPB;   // staging passes
  constexpr int HT    = 64 / RB;           // h-tiles per image
  constexpr int NBLK  = 32 * HT;

  __shared__ __align__(16) union U {
    bf16 xs[2][SLOTS * 8];
    bf16 ep[RB * 64 * 72];
  } sm;

  const int tid  = threadIdx.x;
  const int wave = tid >> 6;
  const int lane = tid & 63;
  const int q    = lane >> 4;
  const int t16  = lane & 15;
  const int rw   = wave / NG;              // output row within block
  const int mt0  = (wave % NG) * MM;
  const int wg   = (int)blockIdx.x;
  const int wgid = XSWZ ? (wg & 7) * (NBLK / 8) + (wg >> 3) : wg;
  const int b    = wgid / HT;
  const int h0   = (wgid % HT) * RB;

  // staging map: chunk id = (r*66 + j)*4 + c8p ; per-pass ids = tid + p*TPB
  const bf16* srcp[P];
  int step[P];
#pragma unroll
  for (int p = 0; p < P; ++p) {
    const int id = tid + p * TPB;
    const int c8p = id & 3, rj = id >> 2;
    const int j = rj % 66, r = rj / 66;
    const int hh = h0 + r - 1, ww = j - 1;
    const bool v = (id < NCHK) && ((unsigned)hh < 64u) && ((unsigned)ww < 64u);
    const int c8 = c8p ^ ((j >> 1) & 3);          // inverse swizzle on source
    srcp[p] = v ? &xin[(((size_t)(b * 64 + hh)) * 64 + ww) * CIN + c8 * 8] : zpage;
    step[p] = v ? 32 : 0;                          // +32 ch per c-iter, pad lanes pinned
  }

  auto stage = [&](char* base) {
#pragma unroll
    for (int p = 0; p < P; ++p) {
      if ((p + 1) * TPB <= NCHK || p * TPB + wave * 64 < NCHK)
        GL16(srcp[p], base + (p * TPB + wave * 64) * 16);
    }
  };

  // B-read base addresses (buf0), one per kw
  int Caddr[3];
#pragma unroll
  for (int kw = 0; kw < 3; ++kw) {
    const int col = t16 + kw;
    Caddr[kw] = rw * 4224 + col * 64 + ((q ^ ((col >> 1) & 3)) << 4);
  }

  char* const lds0 = (char*)&sm.xs[0][0];

  // prologue: stage chunk 0 only (chunk 1 staged under chunk 0's MFMA phase)
  stage(lds0);
#pragma unroll
  for (int p = 0; p < P; ++p) srcp[p] += step[p];
  MEMFENCE();

  // A-fragment 2-slot ping-pong: aE = tap0
  bf16x8 aE[MM], aO[MM];
#pragma unroll
  for (int mm = 0; mm < MM; ++mm)
    aE[mm] = *(const bf16x8*)&wpk[((size_t)(mt0 + mm) * 64 + lane) * 8];

  f32x4 acc[4][MM] = {};
  int tog = BUFB;

  for (int ci = 0; ci < NC; ++ci) {
    if (ci == 0) {
      vwait<MM>();                         // chunk0 GL16s retired; aE in flight
      __builtin_amdgcn_s_barrier();
    } else {
      vwait<2 * MM>();                     // GL16s retired; tap8+next-tap0 in flight
      __builtin_amdgcn_s_barrier();
    }
    if (ci + 1 < NC) {                     // issue next chunk's loads under MFMA
      stage(lds0 + (((ci + 1) & 1) ? BUFB : 0));
#pragma unroll
      for (int p = 0; p < P; ++p) srcp[p] += step[p];
    }
    MEMFENCE();                            // GL16 issue pinned before A/B reads
    // B-fragment double buffer: pre-read tap0
    bf16x8 bb0[4], bb1[4];
#pragma unroll
    for (int nt = 0; nt < 4; ++nt)
      bb0[nt] = *(const bf16x8*)(lds0 + (Caddr[0] + nt * 1024));
    __builtin_amdgcn_s_setprio(1);
#pragma unroll
    for (int pos = 0; pos < 9; ++pos) {
      bf16x8* bc = (pos & 1) ? bb1 : bb0;
      bf16x8* bn = (pos & 1) ? bb0 : bb1;
      if (pos < 8) {                       // issue tap pos+1 B-reads first
        const int kh1 = (pos + 1) / 3, kw1 = (pos + 1) % 3;
#pragma unroll
        for (int nt = 0; nt < 4; ++nt)
          bn[nt] = *(const bf16x8*)(lds0 + (Caddr[kw1] + nt * 1024 + kh1 * 4224));
      }
      bf16x8* ac = (pos & 1) ? aO : aE;
      bf16x8* an = (pos & 1) ? aE : aO;
      if (pos < 8) {                       // A prefetch one tap ahead
        const int ksn = (pos + 1) * NC + ci;
#pragma unroll
        for (int mm = 0; mm < MM; ++mm)
          an[mm] = *(const bf16x8*)&wpk[((size_t)(ksn * NMT + mt0 + mm) * 64 + lane) * 8];
      }
#pragma unroll
      for (int nt = 0; nt < 4; ++nt)
#pragma unroll
        for (int mm = 0; mm < MM; ++mm)
          acc[nt][mm] = __builtin_amdgcn_mfma_f32_16x16x32_bf16(ac[mm], bc[nt], acc[nt][mm], 0, 0, 0);
      if (pos == 8 && ci + 1 < NC) {       // next c-iter tap0 AFTER consuming aE
#pragma unroll
        for (int mm = 0; mm < MM; ++mm)
          aE[mm] = *(const bf16x8*)&wpk[((size_t)((ci + 1) * NMT + mt0 + mm) * 64 + lane) * 8];
      }
    }
    __builtin_amdgcn_s_setprio(0);
#pragma unroll
    for (int kw = 0; kw < 3; ++kw) Caddr[kw] += tog;   // buffer toggle
    tog = -tog;
  }

  // epilogue: BN + SiLU; fp32 NCHW stores for o < C1
  const int h = h0 + rw;
#pragma unroll
  for (int mm = 0; mm < MM; ++mm) {
    const int o0 = (mt0 + mm) * 16 + 4 * q;
    float av[4], bv2[4];
#pragma unroll
    for (int i = 0; i < 4; ++i) { av[i] = alpha[o0 + i]; bv2[i] = beta[o0 + i]; }
#pragma unroll
    for (int nt = 0; nt < 4; ++nt) {
      const int wv = nt * 16 + t16;
#pragma unroll
      for (int i = 0; i < 4; ++i) {
        float v = acc[nt][mm][i] * av[i] + bv2[i];
        float sg = v / (1.f + __expf(-v));
        acc[nt][mm][i] = sg;
        if (o0 < C1)
          out[(((size_t)(b * 256 + chan_off + o0 + i)) * 64 + h) * 64 + wv] = sg;
      }
    }
  }
  if (HASPAD) {
    __syncthreads();                       // full sync: xs dead -> reuse as ep
#pragma unroll
    for (int mm = 0; mm < MM; ++mm) {
      const int o0 = (mt0 + mm) * 16 + 4 * q;
      if (o0 >= C1) {
#pragma unroll
        for (int nt = 0; nt < 4; ++nt) {
          const int px = rw * 64 + nt * 16 + t16;
          union { bf16 h4[4]; uint2 u; } pk;
#pragma unroll
          for (int i = 0; i < 4; ++i) pk.h4[i] = (bf16)acc[nt][mm][i];
          *(uint2*)&sm.ep[px * 72 + (o0 - C1)] = pk.u;
        }
      }
    }
    __syncthreads();
    constexpr int EPP = (RB * 64 * 8) / TPB;
#pragma unroll
    for (int p = 0; p < EPP; ++p) {
      int id = tid + p * TPB;              // RB*64*8 chunks = RB*64 px x 8
      int c8 = id & 7, px = id >> 3;
      bf16x8 v = *(const bf16x8*)&sm.ep[px * 72 + c8 * 8];
      const int r = px >> 6, wv2 = px & 63;
      *(bf16x8*)&padout[(((size_t)(b * 64 + h0 + r)) * 64 + wv2) * 64 + c8 * 8] = v;
    }
  }
}

extern "C" void kernel_launch(void* const* d_in, const int* in_sizes, int n_in,
                              void* d_out, int out_size, void* d_ws, size_t ws_size,
                              hipStream_t stream) {
  QArgs qa;
  const float* x = (const float*)d_in[0];
  for (int L = 0; L < 5; ++L) {
    qa.w[L]  = (const float*)d_in[1 + 5 * L];
    qa.g[L]  = (const float*)d_in[2 + 5 * L];
    qa.bb[L] = (const float*)d_in[3 + 5 * L];
    qa.m[L]  = (const float*)d_in[4 + 5 * L];
    qa.v[L]  = (const float*)d_in[5 + 5 * L];
  }
  char* p = (char*)d_ws;
  bf16* wpk1 = (bf16*)p; p += (size_t)192 * 2304 * 2;
  bf16* wpk2 = (bf16*)p; p += (size_t)128 * 576 * 2;
  bf16* wpk3 = (bf16*)p; p += (size_t)64 * 576 * 2;
  float* a1 = (float*)p; p += 1024;
  float* b1 = (float*)p; p += 1024;
  float* a2 = (float*)p; p += 1024;
  float* b2 = (float*)p; p += 1024;
  float* a3 = (float*)p; p += 1024;
  float* b3 = (float*)p; p += 1024;
  float* zp = (float*)p; p += 128;                             // 128B zero page
  bf16* xT   = (bf16*)p; p += (size_t)32 * 64 * 64 * 256 * 2;  // 67.1 MB
  bf16* stem = (bf16*)p; p += (size_t)32 * 64 * 64 * 64 * 2;   // 16.8 MB
  bf16* tbuf = xT;                                             // alias: xT dead after stage 1
  qa.wpk[0] = wpk1; qa.wpk[1] = wpk2; qa.wpk[2] = wpk3;
  qa.alpha[0] = a1; qa.alpha[1] = a2; qa.alpha[2] = a3;
  qa.beta[0]  = b1; qa.beta[1]  = b2; qa.beta[2]  = b3;

  prep_k<<<384 + 32 * 64 * 4, 256, 0, stream>>>(qa, x, xT, zp);

  const bf16* zpb = (const bf16*)zp;
  conv_k<256, 12, 3, 128, true,  512, 2, false><<<1024,  512, 0, stream>>>(xT,   wpk1, a1, b1, (float*)d_out, 0,   stem, zpb);
  conv_k< 64,  8, 2,  64, true, 1024, 4, true ><<< 512, 1024, 0, stream>>>(stem, wpk2, a2, b2, (float*)d_out, 128, tbuf, zpb);
  conv_k< 64,  4, 2,  64, false, 512, 4, true ><<< 512,  512, 0, stream>>>(tbuf, wpk3, a3, b3, (float*)d_out, 192, nullptr, zpb);
}

// Round 14
// 413.961 us; speedup vs baseline: 1.0856x; 1.0210x over previous
//
#include <hip/hip_runtime.h>
#include <stdint.h>

#define EPSF 1e-5f

typedef __bf16 bf16;
typedef __attribute__((ext_vector_type(8))) __bf16 bf16x8;
typedef __attribute__((ext_vector_type(4))) float f32x4;

// async global->LDS, 16B per lane, dest = wave-uniform base + lane*16 (linear)
#define GL16(src, dst) __builtin_amdgcn_global_load_lds( \
    (const __attribute__((address_space(1))) void*)(src), \
    (__attribute__((address_space(3))) void*)(dst), 16, 0, 0)
// IR+ISA ordering fence for memory ops (pins GL16 issue order vs A-loads/ds_reads)
#define MEMFENCE() asm volatile("" ::: "memory")

// counted vmcnt. Ledger per wait site (R7-derived, R8-verified):
//  - ci==0 (all NC): outstanding = GL16s + MM aE-loads -> vwait<MM> retires ALL
//    GL16s (both sub-buffers for NC==2), keeps aE in flight.
//  - ci>=1 (NC>2): newest 2*MM = pos7 tap8-loads + pos8 next-tap0 loads; vmcnt(2*MM)
//    retires everything older incl. chunk ci's GL16s (issued at top of iter ci-1).
template<int N> __device__ __forceinline__ void vwait() {
  static_assert(N == 2 || N == 3 || N == 4 || N == 6, "unsupported vmcnt");
  if constexpr (N == 2) asm volatile("s_waitcnt vmcnt(2)" ::: "memory");
  else if constexpr (N == 3) asm volatile("s_waitcnt vmcnt(3)" ::: "memory");
  else if constexpr (N == 4) asm volatile("s_waitcnt vmcnt(4)" ::: "memory");
  else asm volatile("s_waitcnt vmcnt(6)" ::: "memory");
}

// ---------------- fused prep: quant (blocks 0..383) + transpose (384..8575) -----
// quant: median via bitwise order-statistic binary search (MSB->LSB), packed
// 16|16 ranks; BN-fold; MFMA A-fragment prepack. transpose: NCHW fp32 -> c-minor
// bf16 xT[b][h][w][256], float4 global loads, float2 LDS reads.
struct QArgs {
  const float* w[5];
  const float* g[5];
  const float* bb[5];
  const float* m[5];
  const float* v[5];
  bf16* wpk[3];
  float* alpha[3];
  float* beta[3];
};

__global__ __launch_bounds__(256)
void prep_k(QArgs qa, const float* __restrict__ x, bf16* __restrict__ xT,
            float* __restrict__ zp) {
  __shared__ int red[2][4];
  __shared__ float tile[64 * 66];
  const int tid = threadIdx.x;
  if (blockIdx.x == 0 && tid < 32) zp[tid] = 0.0f;   // 128B zero page

  if (blockIdx.x < 384) {
    // ---------------- quant branch ----------------
    const int blk = blockIdx.x;
    int layer, o;
    if (blk < 128)      { layer = 0; o = blk; }
    else if (blk < 192) { layer = 1; o = blk - 128; }
    else if (blk < 256) { layer = 2; o = blk - 192; }
    else if (blk < 320) { layer = 3; o = blk - 256; }
    else                { layer = 4; o = blk - 320; }
    const int I_[5]     = {256, 256, 64, 64, 64};
    const int gemm_[5]  = {0, 0, 1, 1, 2};
    const int obase_[5] = {0, 128, 0, 64, 0};
    const int gNMT[3]   = {12, 8, 4};
    const int I = I_[layer];
    const int n = I * 9;                       // 2304 or 576
    const float* w = qa.w[layer] + (size_t)o * n;

    unsigned key[9];
#pragma unroll
    for (int j = 0; j < 9; ++j) key[j] = 0xFFFFFFFFu;   // pad: never < cand
    {
      int c2 = 0;
      for (int i = tid; i < n; i += 256) key[c2++] = __float_as_uint(fabsf(w[i]));
    }

    const int wv = tid >> 6;
    unsigned pfx[2] = {0u, 0u};
    const int rank0 = n / 2 - 1, rank1 = n / 2;
    int pp = 0;
    for (int bit = 31; bit >= 0; --bit) {
      const unsigned c0 = pfx[0] | (1u << bit);
      const unsigned c1 = pfx[1] | (1u << bit);
      int loc = 0;
#pragma unroll
      for (int j = 0; j < 9; ++j)
        loc += (key[j] < c0 ? 1 : 0) + (key[j] < c1 ? 0x10000 : 0);
      loc += __shfl_xor(loc, 32); loc += __shfl_xor(loc, 16);
      loc += __shfl_xor(loc, 8);  loc += __shfl_xor(loc, 4);
      loc += __shfl_xor(loc, 2);  loc += __shfl_xor(loc, 1);
      if ((tid & 63) == 0) red[pp][wv] = loc;
      __syncthreads();
      const int tot = red[pp][0] + red[pp][1] + red[pp][2] + red[pp][3];
      if ((tot & 0xFFFF) <= rank0) pfx[0] = c0;
      if ((tot >> 16)    <= rank1) pfx[1] = c1;
      pp ^= 1;
    }
    const float s =
        fmaxf(0.5f * (__uint_as_float(pfx[0]) + __uint_as_float(pfx[1])), EPSF);

    const int g  = gemm_[layer];
    const int ob = obase_[layer];
    const int NMT = gNMT[g];
    if (tid == 0) {
      float inv = qa.g[layer][o] / sqrtf(qa.v[layer][o] + EPSF);
      qa.alpha[g][ob + o] = s * inv;
      qa.beta[g][ob + o]  = qa.bb[layer][o] - qa.m[layer][o] * inv;
    }
    const int og  = ob + o;
    const int mt  = og >> 4;
    const int l16 = og & 15;
    bf16* wp = qa.wpk[g];
    for (int i = tid; i < n; i += 256) {
      float t = rintf(w[i] / s);
      t = fmaxf(-1.f, fminf(1.f, t));
      int c = i / 9, pos = i % 9;
      int k = pos * I + c;
      int ks = k >> 5, kq = (k >> 3) & 3, jj = k & 7;
      wp[((size_t)((ks * NMT + mt) * 64 + kq * 16 + l16)) * 8 + jj] = (bf16)t;
    }
    return;
  }

  // ---------------- transpose branch ----------------
  const int blk = blockIdx.x - 384;
  const int cg = blk & 3;
  const int h  = (blk >> 2) & 63;
  const int b  = blk >> 8;
  const int w4 = (tid & 15) * 4;
  const int cb = tid >> 4;               // 0..15
#pragma unroll
  for (int p = 0; p < 4; ++p) {
    int c = cb + p * 16;
    const float4 v =
        *(const float4*)&x[(((size_t)(b * 256 + cg * 64 + c)) * 64 + h) * 64 + w4];
    tile[(w4 + 0) * 66 + c] = v.x;
    tile[(w4 + 1) * 66 + c] = v.y;
    tile[(w4 + 2) * 66 + c] = v.z;
    tile[(w4 + 3) * 66 + c] = v.w;
  }
  __syncthreads();
#pragma unroll
  for (int p = 0; p < 2; ++p) {
    int id = tid + p * 256;
    int c8 = id & 7, w2 = id >> 3;
    const float* src = &tile[w2 * 66 + c8 * 8];
    float2 f0 = *(const float2*)(src + 0);
    float2 f1 = *(const float2*)(src + 2);
    float2 f2 = *(const float2*)(src + 4);
    float2 f3 = *(const float2*)(src + 6);
    bf16x8 v;
    v[0] = (bf16)f0.x; v[1] = (bf16)f0.y; v[2] = (bf16)f1.x; v[3] = (bf16)f1.y;
    v[4] = (bf16)f2.x; v[5] = (bf16)f2.y; v[6] = (bf16)f3.x; v[7] = (bf16)f3.y;
    *(bf16x8*)&xT[(((size_t)(b * 64 + h)) * 64 + w2) * 256 + cg * 64 + c8 * 8] = v;
  }
}

// ---------------- implicit-GEMM conv3x3 (pad=1) + fused BN + SiLU ----------------
// R8 structure — session-best measured configuration (417.7 us total).
// BK=32 per barrier, B-fragment register dbuf one tap ahead, A 2-slot ping-pong
// with cross-barrier tap0, global_load_lds w=16, chunk XOR-swizzle on global
// source + read side (G21). Per-wave tile 48ch x 64px (m_w+n_w minimal).
//   conv1: TPB=512, RB=2 (2 blocks/CU barrier overlap partner)
//   conv2: TPB=1024, RB=4, MM=2
//   conv3: TPB=512,  RB=4, MM=2
// NC==2: both sub-chunks staged up front, ONE barrier (R13 A/B: pipelining the
// second stage under MFMA measured -5us — up-front is optimal here).
template<int CIN, int NMT, int MM, int C1, bool HASPAD, int TPB, int RB, bool XSWZ>
__global__ __launch_bounds__(TPB, 4)
void conv_k(const bf16* __restrict__ xin,   // [B][64][64][CIN] c-minor bf16
            const bf16* __restrict__ wpk,
            const float* __restrict__ alpha,
            const float* __restrict__ beta,
            float* __restrict__ out, int chan_off,
            bf16* __restrict__ padout,      // [B][64][64][64] c-minor bf16
            const bf16* __restrict__ zpage) {
  constexpr int NC    = CIN / 32;
  constexpr int NG    = NMT / MM;          // m-groups per row
  constexpr int RS    = RB + 2;            // staged rows incl. halo
  constexpr int NCHK  = RS * 66 * 4;       // live 16B chunks per buffer
  constexpr int SLOTS = (RB == 2) ? 1088 : 1600;  // +guard (wave-granular GL16)
  constexpr int BUFB  = SLOTS * 16;        // buffer stride, bytes
  constexpr int P     = (NCHK + TPB - 1) / TPB;   // staging passes
  constexpr int HT    = 64 / RB;           // h-tiles per image
  constexpr int NBLK  = 32 * HT;

  __shared__ __align__(16) union U {
    bf16 xs[2][SLOTS * 8];
    bf16 ep[RB * 64 * 72];
  } sm;

  const int tid  = threadIdx.x;
  const int wave = tid >> 6;
  const int lane = tid & 63;
  const int q    = lane >> 4;
  const int t16  = lane & 15;
  const int rw   = wave / NG;              // output row within block
  const int mt0  = (wave % NG) * MM;
  const int wg   = (int)blockIdx.x;
  const int wgid = XSWZ ? (wg & 7) * (NBLK / 8) + (wg >> 3) : wg;
  const int b    = wgid / HT;
  const int h0   = (wgid % HT) * RB;

  // staging map: chunk id = (r*66 + j)*4 + c8p ; per-pass ids = tid + p*TPB
  const bf16* srcp[P];
  int step[P];
#pragma unroll
  for (int p = 0; p < P; ++p) {
    const int id = tid + p * TPB;
    const int c8p = id & 3, rj = id >> 2;
    const int j = rj % 66, r = rj / 66;
    const int hh = h0 + r - 1, ww = j - 1;
    const bool v = (id < NCHK) && ((unsigned)hh < 64u) && ((unsigned)ww < 64u);
    const int c8 = c8p ^ ((j >> 1) & 3);          // inverse swizzle on source
    srcp[p] = v ? &xin[(((size_t)(b * 64 + hh)) * 64 + ww) * CIN + c8 * 8] : zpage;
    step[p] = v ? 32 : 0;                          // +32 ch per c-iter, pad lanes pinned
  }

  auto stage = [&](char* base, bool second) {
#pragma unroll
    for (int p = 0; p < P; ++p) {
      if ((p + 1) * TPB <= NCHK || p * TPB + wave * 64 < NCHK)
        GL16(srcp[p] + (second ? step[p] : 0), base + (p * TPB + wave * 64) * 16);
    }
  };

  // B-read base addresses (buf0), one per kw
  int Caddr[3];
#pragma unroll
  for (int kw = 0; kw < 3; ++kw) {
    const int col = t16 + kw;
    Caddr[kw] = rw * 4224 + col * 64 + ((q ^ ((col >> 1) & 3)) << 4);
  }

  char* const lds0 = (char*)&sm.xs[0][0];

  // prologue staging
  stage(lds0, false);
  if constexpr (NC == 2) {
    stage(lds0 + BUFB, true);              // second 32-ch chunk, pad-safe via step
  } else {
#pragma unroll
    for (int p = 0; p < P; ++p) srcp[p] += step[p];
  }
  MEMFENCE();

  // A-fragment 2-slot ping-pong: aE = tap0
  bf16x8 aE[MM], aO[MM];
#pragma unroll
  for (int mm = 0; mm < MM; ++mm)
    aE[mm] = *(const bf16x8*)&wpk[((size_t)(mt0 + mm) * 64 + lane) * 8];

  f32x4 acc[4][MM] = {};
  int tog = BUFB;

  for (int ci = 0; ci < NC; ++ci) {
    if (ci == 0) {
      vwait<MM>();                         // ALL GL16s retired; aE stays in flight
      __builtin_amdgcn_s_barrier();
    } else if constexpr (NC > 2) {
      vwait<2 * MM>();                     // GL16s retired; tap8+next-tap0 in flight
      __builtin_amdgcn_s_barrier();
    }
    if constexpr (NC > 2) {
      if (ci + 1 < NC) {                   // issue next chunk's direct-to-LDS loads
        stage(lds0 + (((ci + 1) & 1) ? BUFB : 0), false);
#pragma unroll
        for (int p = 0; p < P; ++p) srcp[p] += step[p];
      }
    }
    MEMFENCE();                            // GL16 issue pinned before A/B reads
    // B-fragment double buffer: pre-read tap0
    bf16x8 bb0[4], bb1[4];
#pragma unroll
    for (int nt = 0; nt < 4; ++nt)
      bb0[nt] = *(const bf16x8*)(lds0 + (Caddr[0] + nt * 1024));
    __builtin_amdgcn_s_setprio(1);
#pragma unroll
    for (int pos = 0; pos < 9; ++pos) {
      bf16x8* bc = (pos & 1) ? bb1 : bb0;
      bf16x8* bn = (pos & 1) ? bb0 : bb1;
      if (pos < 8) {                       // issue tap pos+1 B-reads first
        const int kh1 = (pos + 1) / 3, kw1 = (pos + 1) % 3;
#pragma unroll
        for (int nt = 0; nt < 4; ++nt)
          bn[nt] = *(const bf16x8*)(lds0 + (Caddr[kw1] + nt * 1024 + kh1 * 4224));
      }
      bf16x8* ac = (pos & 1) ? aO : aE;
      bf16x8* an = (pos & 1) ? aE : aO;
      if (pos < 8) {                       // A prefetch one tap ahead
        const int ksn = (pos + 1) * NC + ci;
#pragma unroll
        for (int mm = 0; mm < MM; ++mm)
          an[mm] = *(const bf16x8*)&wpk[((size_t)(ksn * NMT + mt0 + mm) * 64 + lane) * 8];
      }
#pragma unroll
      for (int nt = 0; nt < 4; ++nt)
#pragma unroll
        for (int mm = 0; mm < MM; ++mm)
          acc[nt][mm] = __builtin_amdgcn_mfma_f32_16x16x32_bf16(ac[mm], bc[nt], acc[nt][mm], 0, 0, 0);
      if (pos == 8 && ci + 1 < NC) {       // next c-iter tap0 AFTER consuming aE
#pragma unroll
        for (int mm = 0; mm < MM; ++mm)
          aE[mm] = *(const bf16x8*)&wpk[((size_t)((ci + 1) * NMT + mt0 + mm) * 64 + lane) * 8];
      }
    }
    __builtin_amdgcn_s_setprio(0);
#pragma unroll
    for (int kw = 0; kw < 3; ++kw) Caddr[kw] += tog;   // buffer toggle
    tog = -tog;
  }

  // epilogue: BN + SiLU; fp32 NCHW stores for o < C1
  const int h = h0 + rw;
#pragma unroll
  for (int mm = 0; mm < MM; ++mm) {
    const int o0 = (mt0 + mm) * 16 + 4 * q;
    float av[4], bv2[4];
#pragma unroll
    for (int i = 0; i < 4; ++i) { av[i] = alpha[o0 + i]; bv2[i] = beta[o0 + i]; }
#pragma unroll
    for (int nt = 0; nt < 4; ++nt) {
      const int wv = nt * 16 + t16;
#pragma unroll
      for (int i = 0; i < 4; ++i) {
        float v = acc[nt][mm][i] * av[i] + bv2[i];
        float sg = v / (1.f + __expf(-v));
        acc[nt][mm][i] = sg;
        if (o0 < C1)
          out[(((size_t)(b * 256 + chan_off + o0 + i)) * 64 + h) * 64 + wv] = sg;
      }
    }
  }
  if (HASPAD) {
    __syncthreads();                       // full sync: xs dead -> reuse as ep
#pragma unroll
    for (int mm = 0; mm < MM; ++mm) {
      const int o0 = (mt0 + mm) * 16 + 4 * q;
      if (o0 >= C1) {
#pragma unroll
        for (int nt = 0; nt < 4; ++nt) {
          const int px = rw * 64 + nt * 16 + t16;
          union { bf16 h4[4]; uint2 u; } pk;
#pragma unroll
          for (int i = 0; i < 4; ++i) pk.h4[i] = (bf16)acc[nt][mm][i];
          *(uint2*)&sm.ep[px * 72 + (o0 - C1)] = pk.u;
        }
      }
    }
    __syncthreads();
    constexpr int EPP = (RB * 64 * 8) / TPB;
#pragma unroll
    for (int p = 0; p < EPP; ++p) {
      int id = tid + p * TPB;              // RB*64*8 chunks = RB*64 px x 8
      int c8 = id & 7, px = id >> 3;
      bf16x8 v = *(const bf16x8*)&sm.ep[px * 72 + c8 * 8];
      const int r = px >> 6, wv2 = px & 63;
      *(bf16x8*)&padout[(((size_t)(b * 64 + h0 + r)) * 64 + wv2) * 64 + c8 * 8] = v;
    }
  }
}

extern "C" void kernel_launch(void* const* d_in, const int* in_sizes, int n_in,
                              void* d_out, int out_size, void* d_ws, size_t ws_size,
                              hipStream_t stream) {
  QArgs qa;
  const float* x = (const float*)d_in[0];
  for (int L = 0; L < 5; ++L) {
    qa.w[L]  = (const float*)d_in[1 + 5 * L];
    qa.g[L]  = (const float*)d_in[2 + 5 * L];
    qa.bb[L] = (const float*)d_in[3 + 5 * L];
    qa.m[L]  = (const float*)d_in[4 + 5 * L];
    qa.v[L]  = (const float*)d_in[5 + 5 * L];
  }
  char* p = (char*)d_ws;
  bf16* wpk1 = (bf16*)p; p += (size_t)192 * 2304 * 2;
  bf16* wpk2 = (bf16*)p; p += (size_t)128 * 576 * 2;
  bf16* wpk3 = (bf16*)p; p += (size_t)64 * 576 * 2;
  float* a1 = (float*)p; p += 1024;
  float* b1 = (float*)p; p += 1024;
  float* a2 = (float*)p; p += 1024;
  float* b2 = (float*)p; p += 1024;
  float* a3 = (float*)p; p += 1024;
  float* b3 = (float*)p; p += 1024;
  float* zp = (float*)p; p += 128;                             // 128B zero page
  bf16* xT   = (bf16*)p; p += (size_t)32 * 64 * 64 * 256 * 2;  // 67.1 MB
  bf16* stem = (bf16*)p; p += (size_t)32 * 64 * 64 * 64 * 2;   // 16.8 MB
  bf16* tbuf = xT;                                             // alias: xT dead after stage 1
  qa.wpk[0] = wpk1; qa.wpk[1] = wpk2; qa.wpk[2] = wpk3;
  qa.alpha[0] = a1; qa.alpha[1] = a2; qa.alpha[2] = a3;
  qa.beta[0]  = b1; qa.beta[1]  = b2; qa.beta[2]  = b3;

  prep_k<<<384 + 32 * 64 * 4, 256, 0, stream>>>(qa, x, xT, zp);

  const bf16* zpb = (const bf16*)zp;
  conv_k<256, 12, 3, 128, true,  512, 2, false><<<1024,  512, 0, stream>>>(xT,   wpk1, a1, b1, (float*)d_out, 0,   stem, zpb);
  conv_k< 64,  8, 2,  64, true, 1024, 4, true ><<< 512, 1024, 0, stream>>>(stem, wpk2, a2, b2, (float*)d_out, 128, tbuf, zpb);
  conv_k< 64,  4, 2,  64, false, 512, 4, true ><<< 512,  512, 0, stream>>>(tbuf, wpk3, a3, b3, (float*)d_out, 192, nullptr, zpb);
}